// Round 2
// baseline (512.717 us; speedup 1.0000x reference)
//
#include <hip/hip_runtime.h>
#include <math.h>

#define SCALE_ 0.08838834764831845f   // 1/sqrt(128)
#define MINV_  (-3.4028234663852886e38f)

typedef __bf16 bf16;
typedef bf16  bf16x4 __attribute__((ext_vector_type(4)));
typedef bf16  bf16x8 __attribute__((ext_vector_type(8)));
typedef float f32x4  __attribute__((ext_vector_type(4)));
typedef float float4v __attribute__((ext_vector_type(4)));

#define LD8(p) (*(const bf16x8*)(p))

__device__ __forceinline__ f32x4 mfma16(bf16x8 a, bf16x8 b, f32x4 c) {
    return __builtin_amdgcn_mfma_f32_16x16x32_bf16(a, b, c, 0, 0, 0);
}

// ---------------- prep kernels ----------------

__global__ __launch_bounds__(256) void cast_hidden_kernel(const float* __restrict__ X, bf16* __restrict__ Y)
{
    int i = (blockIdx.x * 256 + threadIdx.x) * 4;
    float4v v = *(const float4v*)(X + i);
    bf16x4 o; o.x = (bf16)v.x; o.y = (bf16)v.y; o.z = (bf16)v.z; o.w = (bf16)v.w;
    *(bf16x4*)(Y + i) = o;
}

// BT[n][k] = W[k][src(n)]; qmap: src = (n>>7)*384 + (n&127) (q columns of Wqkv), else src=n (Wo)
__global__ __launch_bounds__(256) void transpose_cast_kernel(const float* __restrict__ W, bf16* __restrict__ BT,
                                                             int srcStride, int qmap)
{
    __shared__ float tile[32][33];
    int k0 = blockIdx.x * 32, n0 = blockIdx.y * 32;
    int c = threadIdx.x & 31, r = threadIdx.x >> 5;   // r in 0..7
    int n = n0 + c;
    int src = qmap ? ((n >> 7) * 384 + (n & 127)) : n;
    #pragma unroll
    for (int rr = 0; rr < 32; rr += 8)
        tile[r + rr][c] = W[(size_t)(k0 + r + rr) * srcStride + src];
    __syncthreads();
    #pragma unroll
    for (int rr = 0; rr < 32; rr += 8)
        BT[(size_t)(n0 + r + rr) * 2048 + k0 + c] = (bf16)tile[c][r + rr];
}

// rows 2048..2303 of BT1: head-averaged k/v weight columns.
__global__ __launch_bounds__(256) void bt1_kv_kernel(const float* __restrict__ Wqkv, bf16* __restrict__ BT1)
{
    int k = blockIdx.x * 256 + threadIdx.x;   // 0..2047
    int j = blockIdx.y;                       // 0..255
    float s = 0.f;
    #pragma unroll
    for (int h = 0; h < 16; h++) s += Wqkv[(size_t)k * 6144 + h * 384 + 128 + j];
    BT1[(size_t)(2048 + j) * 2048 + k] = (bf16)(s * 0.0625f);
}

__global__ void bias1_kernel(const float* __restrict__ bqkv, float* __restrict__ bias1)
{
    int c = blockIdx.x * 256 + threadIdx.x;
    if (c >= 2304) return;
    if (c < 2048) bias1[c] = bqkv[(c >> 7) * 384 + (c & 127)];
    else {
        int j = c - 2048; float s = 0.f;
        for (int h = 0; h < 16; h++) s += bqkv[h * 384 + 128 + j];
        bias1[c] = s * 0.0625f;
    }
}

// ---------------- GEMM: C[m][n] = A[m][:] . BT[n][:] + bias[n] ----------------
template<int OUT_BF16>
__global__ __launch_bounds__(256) void gemm_kernel(const bf16* __restrict__ A, const bf16* __restrict__ BT,
                                                   const float* __restrict__ bias, void* __restrict__ Cout,
                                                   int M, int N, int K)
{
    __shared__ bf16 As[128 * 32];
    __shared__ bf16 Bs[128 * 32];
    const int tid  = threadIdx.x;
    const int wv   = tid >> 6, lane = tid & 63, quad = lane >> 4, l16 = lane & 15;
    const int wrow = wv >> 1, wcol = wv & 1;
    const int m0 = blockIdx.y * 128, n0 = blockIdx.x * 128;

    const int srow = tid >> 1, scol = (tid & 1) * 16;
    const bf16* Ag = A  + (size_t)(m0 + srow) * K + scol;
    const bf16* Bg = BT + (size_t)(n0 + srow) * K + scol;

    f32x4 acc[4][4];
    #pragma unroll
    for (int i = 0; i < 4; i++)
        #pragma unroll
        for (int j = 0; j < 4; j++) acc[i][j] = (f32x4){0.f, 0.f, 0.f, 0.f};

    for (int kk = 0; kk < K; kk += 32) {
        bf16x8 av0 = LD8(Ag + kk);
        bf16x8 av1 = LD8(Ag + kk + 8);
        bf16x8 bv0 = LD8(Bg + kk);
        bf16x8 bv1 = LD8(Bg + kk + 8);
        *(bf16x8*)&As[srow * 32 + scol]     = av0;
        *(bf16x8*)&As[srow * 32 + scol + 8] = av1;
        *(bf16x8*)&Bs[srow * 32 + scol]     = bv0;
        *(bf16x8*)&Bs[srow * 32 + scol + 8] = bv1;
        __syncthreads();
        bf16x8 af[4], bfr[4];
        #pragma unroll
        for (int i = 0; i < 4; i++) af[i]  = LD8(&As[(wrow * 64 + i * 16 + l16) * 32 + quad * 8]);
        #pragma unroll
        for (int j = 0; j < 4; j++) bfr[j] = LD8(&Bs[(wcol * 64 + j * 16 + l16) * 32 + quad * 8]);
        #pragma unroll
        for (int i = 0; i < 4; i++)
            #pragma unroll
            for (int j = 0; j < 4; j++)
                acc[i][j] = mfma16(af[i], bfr[j], acc[i][j]);
        __syncthreads();
    }

    #pragma unroll
    for (int i = 0; i < 4; i++) {
        #pragma unroll
        for (int j = 0; j < 4; j++) {
            int n = n0 + wcol * 64 + j * 16 + l16;
            float bn = bias[n];
            #pragma unroll
            for (int r = 0; r < 4; r++) {
                int m = m0 + wrow * 64 + i * 16 + quad * 4 + r;
                float v = acc[i][j][r] + bn;
                if (OUT_BF16) ((bf16*)Cout)[(size_t)m * N + n] = (bf16)v;
                else          ((float*)Cout)[(size_t)m * N + n] = v;
            }
        }
    }
}

// ---------------- rotary (in-place on C1 bf16): q (16 heads) + k_mean, first 32 dims ----------------
__global__ __launch_bounds__(320) void rotary_kernel(bf16* __restrict__ C1)
{
    int row = blockIdx.x;          // b*2048 + s
    int s = row & 2047;
    int t = threadIdx.x;
    if (t >= 272) return;          // 17 groups (16 q heads + k_mean) x 16 dim-pairs
    int g = t >> 4, dd = t & 15;
    bf16* ptr = C1 + (size_t)row * 2304 + (g < 16 ? g * 128 : 2048);
    float x0 = (float)ptr[dd], x1 = (float)ptr[dd + 16];
    const float L = 0.575646273248511f;  // ln(10000)/16
    float inv = expf(-L * (float)dd);
    float ang = (float)s * inv;
    float c = cosf(ang), si = sinf(ang);
    ptr[dd]      = (bf16)(x0 * c - x1 * si);
    ptr[dd + 16] = (bf16)(x1 * c + x0 * si);
}

// ---------------- vmT[b][d][s] = v_mean transposed; vgT[b][d][g] = gathered global v ----------------
__global__ __launch_bounds__(256) void build_vmT_kernel(const bf16* __restrict__ C1, bf16* __restrict__ vmT)
{
    __shared__ float tile[32][33];
    int b = blockIdx.z;
    int s0 = blockIdx.x * 32, d0 = blockIdx.y * 32;
    int c = threadIdx.x & 31, r = threadIdx.x >> 5;
    #pragma unroll
    for (int rr = 0; rr < 32; rr += 8)
        tile[r + rr][c] = (float)C1[(size_t)(b * 2048 + s0 + r + rr) * 2304 + 2176 + d0 + c];
    __syncthreads();
    #pragma unroll
    for (int rr = 0; rr < 32; rr += 8)
        vmT[(size_t)(b * 128 + d0 + r + rr) * 2048 + s0 + c] = (bf16)tile[c][r + rr];
}

__global__ void build_vgT_kernel(const bf16* __restrict__ C1, const int* __restrict__ gidx, bf16* __restrict__ vgT)
{
    int b = blockIdx.x;
    for (int i = threadIdx.x; i < 128 * 64; i += 256) {
        int d = i >> 6, g = i & 63;
        int pos = gidx[b * 64 + g];
        vgT[(size_t)(b * 128 + d) * 64 + g] = C1[(size_t)(b * 2048 + pos) * 2304 + 2176 + d];
    }
}

// ---------------- attention, first WIN=256 queries (causal), block per (qtile16, h, b) ----------------
__global__ __launch_bounds__(256) void attn0_kernel(const bf16* __restrict__ C1, const bf16* __restrict__ vmT,
                                                    const float* __restrict__ mask, bf16* __restrict__ attn)
{
    int qt = blockIdx.x, h = blockIdx.y, b = blockIdx.z;
    int tid = threadIdx.x, wv = tid >> 6, lane = tid & 63, quad = lane >> 4, l16 = lane & 15;
    int q0 = qt * 16;

    __shared__ float s_s[16][264];
    __shared__ bf16  p_s[16][272];
    __shared__ float inv_l[16];

    bf16x8 af[4];
    const bf16* qbase = C1 + (size_t)(b * 2048 + q0 + l16) * 2304 + h * 128;
    #pragma unroll
    for (int ks = 0; ks < 4; ks++) af[ks] = LD8(qbase + ks * 32 + quad * 8);

    f32x4 acc[4];
    #pragma unroll
    for (int t = 0; t < 4; t++) acc[t] = (f32x4){0.f, 0.f, 0.f, 0.f};
    #pragma unroll
    for (int t = 0; t < 4; t++) {
        int key = (wv * 4 + t) * 16 + l16;
        const bf16* kb = C1 + (size_t)(b * 2048 + key) * 2304 + 2048;
        #pragma unroll
        for (int ks = 0; ks < 4; ks++)
            acc[t] = mfma16(af[ks], LD8(kb + ks * 32 + quad * 8), acc[t]);
    }
    #pragma unroll
    for (int t = 0; t < 4; t++) {
        int key = (wv * 4 + t) * 16 + l16;
        float mval = mask[b * 2048 + key];
        #pragma unroll
        for (int r = 0; r < 4; r++) {
            int qq = q0 + quad * 4 + r;
            float s = acc[t][r] * SCALE_;
            if (key > qq) s = MINV_;
            s_s[quad * 4 + r][key] = s + mval;
        }
    }
    __syncthreads();

    int g = tid >> 4, lg = tid & 15;
    float vals[16];
    float mx = MINV_;
    #pragma unroll
    for (int i = 0; i < 16; i++) { vals[i] = s_s[g][lg + 16 * i]; mx = fmaxf(mx, vals[i]); }
    #pragma unroll
    for (int m = 1; m < 16; m <<= 1) mx = fmaxf(mx, __shfl_xor(mx, m, 64));
    float l = 0.f;
    #pragma unroll
    for (int i = 0; i < 16; i++) { float e = expf(vals[i] - mx); l += e; p_s[g][lg + 16 * i] = (bf16)e; }
    #pragma unroll
    for (int m = 1; m < 16; m <<= 1) l += __shfl_xor(l, m, 64);
    if (lg == 0) inv_l[g] = 1.0f / l;
    __syncthreads();

    f32x4 o[2];
    o[0] = (f32x4){0.f, 0.f, 0.f, 0.f}; o[1] = (f32x4){0.f, 0.f, 0.f, 0.f};
    #pragma unroll
    for (int ks = 0; ks < 8; ks++) {
        bf16x8 pa = LD8(&p_s[l16][ks * 32 + quad * 8]);
        #pragma unroll
        for (int t = 0; t < 2; t++) {
            int d = wv * 32 + t * 16 + l16;
            bf16x8 vb = LD8(vmT + (size_t)(b * 128 + d) * 2048 + ks * 32 + quad * 8);
            o[t] = mfma16(pa, vb, o[t]);
        }
    }
    #pragma unroll
    for (int t = 0; t < 2; t++) {
        int d = wv * 32 + t * 16 + l16;
        #pragma unroll
        for (int r = 0; r < 4; r++) {
            int qq = q0 + quad * 4 + r;
            attn[(size_t)(b * 2048 + qq) * 2048 + h * 128 + d] = (bf16)(o[t][r] * inv_l[quad * 4 + r]);
        }
    }
}

// ---------------- attention steps v2: flash-style, 4 steps x 16 heads per block ----------------
// Block = (sb, b): steps step0..step0+3, wave wv owns step step0+wv (m-tile rows = 16 heads).
// Keys in 6 chunks of 64: chunk 0 = 64 global keys, chunks 1..5 = window w in [0,320).
// Online softmax (running m,l per head) with P transposed via per-wave LDS scratch.
__global__ __launch_bounds__(256) void attn_steps2_kernel(const bf16* __restrict__ C1, const bf16* __restrict__ vmT,
                                                          const bf16* __restrict__ vgT, const float* __restrict__ mask,
                                                          const int* __restrict__ gidx, bf16* __restrict__ attn)
{
    const int sb = blockIdx.x, b = blockIdx.y;
    const int step0 = sb * 4;
    const int tid = threadIdx.x, wv = tid >> 6, lane = tid & 63, quad = lane >> 4, l16 = lane & 15;
    const int step = step0 + wv, p = 256 + step;

    __shared__ __align__(16) bf16 Ks[64 * 136];      // staged keys, stride 136 (2-way banks = free)
    __shared__ __align__(16) bf16 Ps[4 * 16 * 72];   // per-wave P transpose scratch, stride 72
    __shared__ int gixs[64];

    if (tid < 64) gixs[tid] = gidx[b * 64 + tid];

    // Q A-fragments: A[m=head=l16][k=quad*8+j]
    bf16x8 af[4];
    const bf16* qrow = C1 + (size_t)(b * 2048 + p) * 2304 + l16 * 128;
    #pragma unroll
    for (int ks = 0; ks < 4; ks++) af[ks] = LD8(qrow + ks * 32 + quad * 8);

    f32x4 m_run = (f32x4){MINV_, MINV_, MINV_, MINV_};
    f32x4 l_run = (f32x4){0.f, 0.f, 0.f, 0.f};
    f32x4 O[8];
    #pragma unroll
    for (int dt = 0; dt < 8; dt++) O[dt] = (f32x4){0.f, 0.f, 0.f, 0.f};

    const int srow = tid >> 2, scol = (tid & 3) * 32;   // staging: 64 rows x 128 el, 4 threads/row
    bf16* Pw = &Ps[wv * (16 * 72)];

    for (int c = 0; c < 6; c++) {
        __syncthreads();   // previous compute done reading Ks (and gixs visible at c=0)
        // ---- stage 64 keys into LDS ----
        {
            int pos;
            if (c == 0) pos = gixs[srow];
            else        pos = min(step0 + 1 + (c - 1) * 64 + srow, 2047);
            const bf16* src = C1 + (size_t)(b * 2048 + pos) * 2304 + 2048 + scol;
            bf16x8 t0 = LD8(src), t1 = LD8(src + 8), t2 = LD8(src + 16), t3 = LD8(src + 24);
            bf16* dst = &Ks[srow * 136 + scol];
            ((bf16x8*)dst)[0] = t0; *(bf16x8*)(dst + 8) = t1;
            *(bf16x8*)(dst + 16) = t2; *(bf16x8*)(dst + 24) = t3;
        }
        __syncthreads();

        // ---- QK^T for this wave's m-tile: 4 n-tiles x 4 k-steps ----
        f32x4 acc[4];
        #pragma unroll
        for (int t = 0; t < 4; t++) acc[t] = (f32x4){0.f, 0.f, 0.f, 0.f};
        #pragma unroll
        for (int t = 0; t < 4; t++) {
            const bf16* kb = &Ks[(t * 16 + l16) * 136];
            #pragma unroll
            for (int ks = 0; ks < 4; ks++)
                acc[t] = mfma16(af[ks], LD8(kb + ks * 32 + quad * 8), acc[t]);
        }

        // ---- mask + scale ----
        float sv[4][4];
        bool vld[4];
        #pragma unroll
        for (int t = 0; t < 4; t++) {
            int key = t * 16 + l16;
            float addv;
            if (c == 0) { vld[t] = gixs[key] < step; addv = 0.f; }
            else {
                int w = (c - 1) * 64 + key;
                vld[t] = (w >= wv) && (w <= wv + 255);
                addv = mask[b * 2048 + min(step0 + 1 + w, 2047)];
            }
            #pragma unroll
            for (int r = 0; r < 4; r++) sv[t][r] = vld[t] ? (acc[t][r] * SCALE_ + addv) : MINV_;
        }

        // ---- online softmax update (row = head = quad*4+r, reduce over 16 lanes of quad) ----
        f32x4 cm;
        #pragma unroll
        for (int r = 0; r < 4; r++) cm[r] = fmaxf(fmaxf(sv[0][r], sv[1][r]), fmaxf(sv[2][r], sv[3][r]));
        #pragma unroll
        for (int ms = 1; ms < 16; ms <<= 1)
            #pragma unroll
            for (int r = 0; r < 4; r++) cm[r] = fmaxf(cm[r], __shfl_xor(cm[r], ms, 64));

        f32x4 nm, alpha;
        #pragma unroll
        for (int r = 0; r < 4; r++) { nm[r] = fmaxf(m_run[r], cm[r]); alpha[r] = expf(m_run[r] - nm[r]); }

        float pv[4][4];
        f32x4 cs = (f32x4){0.f, 0.f, 0.f, 0.f};
        #pragma unroll
        for (int t = 0; t < 4; t++)
            #pragma unroll
            for (int r = 0; r < 4; r++) {
                pv[t][r] = vld[t] ? expf(sv[t][r] - nm[r]) : 0.f;
                cs[r] += pv[t][r];
            }
        #pragma unroll
        for (int ms = 1; ms < 16; ms <<= 1)
            #pragma unroll
            for (int r = 0; r < 4; r++) cs[r] += __shfl_xor(cs[r], ms, 64);

        m_run = nm;
        #pragma unroll
        for (int r = 0; r < 4; r++) l_run[r] = l_run[r] * alpha[r] + cs[r];
        #pragma unroll
        for (int dt = 0; dt < 8; dt++)
            #pragma unroll
            for (int r = 0; r < 4; r++) O[dt][r] *= alpha[r];

        // ---- P: C-layout -> LDS -> A-layout (per-wave scratch, no barrier) ----
        #pragma unroll
        for (int t = 0; t < 4; t++)
            #pragma unroll
            for (int r = 0; r < 4; r++)
                Pw[(quad * 4 + r) * 72 + t * 16 + l16] = (bf16)pv[t][r];
        bf16x8 pa0 = LD8(&Pw[l16 * 72 + quad * 8]);
        bf16x8 pa1 = LD8(&Pw[l16 * 72 + 32 + quad * 8]);

        // ---- PV: 8 d-tiles x 2 k-steps ----
        #pragma unroll
        for (int dt = 0; dt < 8; dt++) {
            int d = dt * 16 + l16;
            const bf16* vb;
            if (c == 0) vb = vgT + (size_t)(b * 128 + d) * 64;
            else        vb = vmT + (size_t)(b * 128 + d) * 2048 + (step0 + 1 + (c - 1) * 64);
            O[dt] = mfma16(pa0, LD8(vb + quad * 8), O[dt]);
            O[dt] = mfma16(pa1, LD8(vb + 32 + quad * 8), O[dt]);
        }
    }

    // ---- epilogue ----
    f32x4 invl;
    #pragma unroll
    for (int r = 0; r < 4; r++) invl[r] = 1.0f / l_run[r];
    #pragma unroll
    for (int dt = 0; dt < 8; dt++)
        #pragma unroll
        for (int r = 0; r < 4; r++) {
            int h = quad * 4 + r;
            attn[(size_t)(b * 2048 + p) * 2048 + h * 128 + dt * 16 + l16] = (bf16)(O[dt][r] * invl[r]);
        }
}

// ---------------- launch ----------------
extern "C" void kernel_launch(void* const* d_in, const int* in_sizes, int n_in,
                              void* d_out, int out_size, void* d_ws, size_t ws_size,
                              hipStream_t stream)
{
    const float* hidden = (const float*)d_in[0];
    const float* amask  = (const float*)d_in[1];
    const int*   gidx   = (const int*)d_in[2];
    const float* Wqkv   = (const float*)d_in[3];
    const float* bqkv   = (const float*)d_in[4];
    const float* Wo     = (const float*)d_in[5];
    const float* bo     = (const float*)d_in[6];

    char* ws = (char*)d_ws;
    size_t off = 0;
    auto take = [&](size_t bytes) -> char* {
        char* p = ws + off;
        off = (off + bytes + 255) & ~(size_t)255;
        return p;
    };
    bf16*  A16   = (bf16*)take(4096ull * 2048 * 2);   // hidden, bf16
    bf16*  BT1   = (bf16*)take(2304ull * 2048 * 2);   // [q cols | k-avg | v-avg]^T
    bf16*  BT2   = (bf16*)take(2048ull * 2048 * 2);   // Wo^T
    bf16*  C1    = (bf16*)take(4096ull * 2304 * 2);   // q(2048) | k_mean(128) | v_mean(128)
    bf16*  vmT   = (bf16*)take(2ull * 128 * 2048 * 2);
    bf16*  vgT   = (bf16*)take(2ull * 128 * 64 * 2);
    bf16*  attnb = (bf16*)take(4096ull * 2048 * 2);
    float* bias1 = (float*)take(2304 * 4);

    cast_hidden_kernel<<<8192, 256, 0, stream>>>(hidden, A16);
    transpose_cast_kernel<<<dim3(64, 64), 256, 0, stream>>>(Wqkv, BT1, 6144, 1);
    bt1_kv_kernel<<<dim3(8, 256), 256, 0, stream>>>(Wqkv, BT1);
    bias1_kernel<<<9, 256, 0, stream>>>(bqkv, bias1);
    transpose_cast_kernel<<<dim3(64, 64), 256, 0, stream>>>(Wo, BT2, 2048, 0);

    gemm_kernel<1><<<dim3(18, 32), 256, 0, stream>>>(A16, BT1, bias1, (void*)C1, 4096, 2304, 2048);

    rotary_kernel<<<4096, 320, 0, stream>>>(C1);
    build_vmT_kernel<<<dim3(64, 4, 2), 256, 0, stream>>>(C1, vmT);
    build_vgT_kernel<<<2, 256, 0, stream>>>(C1, gidx, vgT);

    attn0_kernel<<<dim3(16, 16, 2), 256, 0, stream>>>(C1, vmT, amask, attnb);
    attn_steps2_kernel<<<dim3(448, 2), 256, 0, stream>>>(C1, vmT, vgT, amask, gidx, attnb);

    gemm_kernel<0><<<dim3(16, 32), 256, 0, stream>>>(attnb, BT2, bo, d_out, 4096, 2048, 2048);

    (void)in_sizes; (void)n_in; (void)out_size; (void)ws_size;
}

// Round 3
// 392.111 us; speedup vs baseline: 1.3076x; 1.3076x over previous
//
#include <hip/hip_runtime.h>
#include <math.h>

#define SCALE_ 0.08838834764831845f   // 1/sqrt(128)
#define MINV_  (-3.4028234663852886e38f)

typedef __bf16 bf16;
typedef bf16  bf16x4 __attribute__((ext_vector_type(4)));
typedef bf16  bf16x8 __attribute__((ext_vector_type(8)));
typedef float f32x4  __attribute__((ext_vector_type(4)));
typedef float float4v __attribute__((ext_vector_type(4)));

#define LD8(p) (*(const bf16x8*)(p))

__device__ __forceinline__ f32x4 mfma16(bf16x8 a, bf16x8 b, f32x4 c) {
    return __builtin_amdgcn_mfma_f32_16x16x32_bf16(a, b, c, 0, 0, 0);
}

// ---------------- prep kernels ----------------

__global__ __launch_bounds__(256) void cast_hidden_kernel(const float* __restrict__ X, bf16* __restrict__ Y)
{
    int i = (blockIdx.x * 256 + threadIdx.x) * 4;
    float4v v = *(const float4v*)(X + i);
    bf16x4 o; o.x = (bf16)v.x; o.y = (bf16)v.y; o.z = (bf16)v.z; o.w = (bf16)v.w;
    *(bf16x4*)(Y + i) = o;
}

// BT[n][k] = W[k][src(n)]; qmap: src = (n>>7)*384 + (n&127) (q columns of Wqkv), else src=n (Wo)
__global__ __launch_bounds__(256) void transpose_cast_kernel(const float* __restrict__ W, bf16* __restrict__ BT,
                                                             int srcStride, int qmap)
{
    __shared__ float tile[32][33];
    int k0 = blockIdx.x * 32, n0 = blockIdx.y * 32;
    int c = threadIdx.x & 31, r = threadIdx.x >> 5;   // r in 0..7
    int n = n0 + c;
    int src = qmap ? ((n >> 7) * 384 + (n & 127)) : n;
    #pragma unroll
    for (int rr = 0; rr < 32; rr += 8)
        tile[r + rr][c] = W[(size_t)(k0 + r + rr) * srcStride + src];
    __syncthreads();
    #pragma unroll
    for (int rr = 0; rr < 32; rr += 8)
        BT[(size_t)(n0 + r + rr) * 2048 + k0 + c] = (bf16)tile[c][r + rr];
}

// rows 2048..2303 of BT1: head-averaged k/v weight columns.
__global__ __launch_bounds__(256) void bt1_kv_kernel(const float* __restrict__ Wqkv, bf16* __restrict__ BT1)
{
    int k = blockIdx.x * 256 + threadIdx.x;   // 0..2047
    int j = blockIdx.y;                       // 0..255
    float s = 0.f;
    #pragma unroll
    for (int h = 0; h < 16; h++) s += Wqkv[(size_t)k * 6144 + h * 384 + 128 + j];
    BT1[(size_t)(2048 + j) * 2048 + k] = (bf16)(s * 0.0625f);
}

__global__ void bias1_kernel(const float* __restrict__ bqkv, float* __restrict__ bias1)
{
    int c = blockIdx.x * 256 + threadIdx.x;
    if (c >= 2304) return;
    if (c < 2048) bias1[c] = bqkv[(c >> 7) * 384 + (c & 127)];
    else {
        int j = c - 2048; float s = 0.f;
        for (int h = 0; h < 16; h++) s += bqkv[h * 384 + 128 + j];
        bias1[c] = s * 0.0625f;
    }
}

// ---------------- GEMM: C[m][n] = A[m][:] . BT[n][:] + bias[n] ----------------
template<int OUT_BF16>
__global__ __launch_bounds__(256) void gemm_kernel(const bf16* __restrict__ A, const bf16* __restrict__ BT,
                                                   const float* __restrict__ bias, void* __restrict__ Cout,
                                                   int M, int N, int K)
{
    __shared__ bf16 As[128 * 32];
    __shared__ bf16 Bs[128 * 32];
    const int tid  = threadIdx.x;
    const int wv   = tid >> 6, lane = tid & 63, quad = lane >> 4, l16 = lane & 15;
    const int wrow = wv >> 1, wcol = wv & 1;
    const int m0 = blockIdx.y * 128, n0 = blockIdx.x * 128;

    const int srow = tid >> 1, scol = (tid & 1) * 16;
    const bf16* Ag = A  + (size_t)(m0 + srow) * K + scol;
    const bf16* Bg = BT + (size_t)(n0 + srow) * K + scol;

    f32x4 acc[4][4];
    #pragma unroll
    for (int i = 0; i < 4; i++)
        #pragma unroll
        for (int j = 0; j < 4; j++) acc[i][j] = (f32x4){0.f, 0.f, 0.f, 0.f};

    for (int kk = 0; kk < K; kk += 32) {
        bf16x8 av0 = LD8(Ag + kk);
        bf16x8 av1 = LD8(Ag + kk + 8);
        bf16x8 bv0 = LD8(Bg + kk);
        bf16x8 bv1 = LD8(Bg + kk + 8);
        *(bf16x8*)&As[srow * 32 + scol]     = av0;
        *(bf16x8*)&As[srow * 32 + scol + 8] = av1;
        *(bf16x8*)&Bs[srow * 32 + scol]     = bv0;
        *(bf16x8*)&Bs[srow * 32 + scol + 8] = bv1;
        __syncthreads();
        bf16x8 af[4], bfr[4];
        #pragma unroll
        for (int i = 0; i < 4; i++) af[i]  = LD8(&As[(wrow * 64 + i * 16 + l16) * 32 + quad * 8]);
        #pragma unroll
        for (int j = 0; j < 4; j++) bfr[j] = LD8(&Bs[(wcol * 64 + j * 16 + l16) * 32 + quad * 8]);
        #pragma unroll
        for (int i = 0; i < 4; i++)
            #pragma unroll
            for (int j = 0; j < 4; j++)
                acc[i][j] = mfma16(af[i], bfr[j], acc[i][j]);
        __syncthreads();
    }

    #pragma unroll
    for (int i = 0; i < 4; i++) {
        #pragma unroll
        for (int j = 0; j < 4; j++) {
            int n = n0 + wcol * 64 + j * 16 + l16;
            float bn = bias[n];
            #pragma unroll
            for (int r = 0; r < 4; r++) {
                int m = m0 + wrow * 64 + i * 16 + quad * 4 + r;
                float v = acc[i][j][r] + bn;
                if (OUT_BF16) ((bf16*)Cout)[(size_t)m * N + n] = (bf16)v;
                else          ((float*)Cout)[(size_t)m * N + n] = v;
            }
        }
    }
}

// ---------------- rotary (in-place on C1 bf16): q (16 heads) + k_mean, first 32 dims ----------------
__global__ __launch_bounds__(320) void rotary_kernel(bf16* __restrict__ C1)
{
    int row = blockIdx.x;          // b*2048 + s
    int s = row & 2047;
    int t = threadIdx.x;
    if (t >= 272) return;          // 17 groups (16 q heads + k_mean) x 16 dim-pairs
    int g = t >> 4, dd = t & 15;
    bf16* ptr = C1 + (size_t)row * 2304 + (g < 16 ? g * 128 : 2048);
    float x0 = (float)ptr[dd], x1 = (float)ptr[dd + 16];
    const float L = 0.575646273248511f;  // ln(10000)/16
    float inv = expf(-L * (float)dd);
    float ang = (float)s * inv;
    float c = cosf(ang), si = sinf(ang);
    ptr[dd]      = (bf16)(x0 * c - x1 * si);
    ptr[dd + 16] = (bf16)(x1 * c + x0 * si);
}

// ---------------- vmT[b][d][s] = v_mean transposed ----------------
__global__ __launch_bounds__(256) void build_vmT_kernel(const bf16* __restrict__ C1, bf16* __restrict__ vmT)
{
    __shared__ float tile[32][33];
    int b = blockIdx.z;
    int s0 = blockIdx.x * 32, d0 = blockIdx.y * 32;
    int c = threadIdx.x & 31, r = threadIdx.x >> 5;
    #pragma unroll
    for (int rr = 0; rr < 32; rr += 8)
        tile[r + rr][c] = (float)C1[(size_t)(b * 2048 + s0 + r + rr) * 2304 + 2176 + d0 + c];
    __syncthreads();
    #pragma unroll
    for (int rr = 0; rr < 32; rr += 8)
        vmT[(size_t)(b * 128 + d0 + r + rr) * 2048 + s0 + c] = (bf16)tile[c][r + rr];
}

// ---------------- pretile K/V into MFMA fragment order at 64-aligned key chunks ----------------
// KF[((b*33+c)*16 + t*4+ks)*512 + lane*8 + j] = K[c*64 + t*16 + (lane&15)][ks*32 + (lane>>4)*8 + j]
// VF[((b*33+c)*16 + dt*2+ks2)*512 + lane*8 + j] = V[c*64 + ks2*32 + (lane>>4)*8 + j][dt*16 + (lane&15)]
__global__ __launch_bounds__(256) void pretile_win_kernel(const bf16* __restrict__ C1, const bf16* __restrict__ vmT,
                                                          bf16* __restrict__ KF, bf16* __restrict__ VF)
{
    int c = blockIdx.x, b = blockIdx.y;
    for (int i = 0; i < 8; i++) {
        int sid = threadIdx.x + i * 256;     // 0..2047
        int lane = sid & 63, fi = (sid >> 6) & 15;
        int l16 = lane & 15, quad = lane >> 4;
        if (sid < 1024) {
            int t = fi >> 2, ks = fi & 3;
            const bf16* src = C1 + (size_t)(b * 2048 + c * 64 + t * 16 + l16) * 2304 + 2048 + ks * 32 + quad * 8;
            *(bf16x8*)&KF[((size_t)(b * 33 + c) * 16 + fi) * 512 + lane * 8] = LD8(src);
        } else {
            int dt = fi >> 1, ks2 = fi & 1;
            const bf16* src = vmT + (size_t)(b * 128 + dt * 16 + l16) * 2048 + c * 64 + ks2 * 32 + quad * 8;
            *(bf16x8*)&VF[((size_t)(b * 33 + c) * 16 + fi) * 512 + lane * 8] = LD8(src);
        }
    }
}

// chunk 32 = 64 gathered global keys
__global__ __launch_bounds__(256) void pretile_glob_kernel(const bf16* __restrict__ C1, const bf16* __restrict__ vmT,
                                                           const int* __restrict__ gidx,
                                                           bf16* __restrict__ KF, bf16* __restrict__ VF)
{
    int b = blockIdx.x;
    for (int i = 0; i < 8; i++) {
        int sid = threadIdx.x + i * 256;
        int lane = sid & 63, fi = (sid >> 6) & 15;
        int l16 = lane & 15, quad = lane >> 4;
        if (sid < 1024) {
            int t = fi >> 2, ks = fi & 3;
            int pos = gidx[b * 64 + t * 16 + l16];
            const bf16* src = C1 + (size_t)(b * 2048 + pos) * 2304 + 2048 + ks * 32 + quad * 8;
            *(bf16x8*)&KF[((size_t)(b * 33 + 32) * 16 + fi) * 512 + lane * 8] = LD8(src);
        } else {
            int dt = fi >> 1, ks2 = fi & 1;
            int d = dt * 16 + l16;
            bf16 tmp[8];
            #pragma unroll
            for (int j = 0; j < 8; j++) {
                int pos = gidx[b * 64 + ks2 * 32 + quad * 8 + j];
                tmp[j] = vmT[(size_t)(b * 128 + d) * 2048 + pos];
            }
            #pragma unroll
            for (int j = 0; j < 8; j++)
                VF[((size_t)(b * 33 + 32) * 16 + fi) * 512 + lane * 8 + j] = tmp[j];
        }
    }
}

// ---------------- attention, first WIN=256 queries (causal), block per (qtile16, h, b) ----------------
__global__ __launch_bounds__(256) void attn0_kernel(const bf16* __restrict__ C1, const bf16* __restrict__ vmT,
                                                    const float* __restrict__ mask, bf16* __restrict__ attn)
{
    int qt = blockIdx.x, h = blockIdx.y, b = blockIdx.z;
    int tid = threadIdx.x, wv = tid >> 6, lane = tid & 63, quad = lane >> 4, l16 = lane & 15;
    int q0 = qt * 16;

    __shared__ float s_s[16][264];
    __shared__ bf16  p_s[16][272];
    __shared__ float inv_l[16];

    bf16x8 af[4];
    const bf16* qbase = C1 + (size_t)(b * 2048 + q0 + l16) * 2304 + h * 128;
    #pragma unroll
    for (int ks = 0; ks < 4; ks++) af[ks] = LD8(qbase + ks * 32 + quad * 8);

    f32x4 acc[4];
    #pragma unroll
    for (int t = 0; t < 4; t++) acc[t] = (f32x4){0.f, 0.f, 0.f, 0.f};
    #pragma unroll
    for (int t = 0; t < 4; t++) {
        int key = (wv * 4 + t) * 16 + l16;
        const bf16* kb = C1 + (size_t)(b * 2048 + key) * 2304 + 2048;
        #pragma unroll
        for (int ks = 0; ks < 4; ks++)
            acc[t] = mfma16(af[ks], LD8(kb + ks * 32 + quad * 8), acc[t]);
    }
    #pragma unroll
    for (int t = 0; t < 4; t++) {
        int key = (wv * 4 + t) * 16 + l16;
        float mval = mask[b * 2048 + key];
        #pragma unroll
        for (int r = 0; r < 4; r++) {
            int qq = q0 + quad * 4 + r;
            float s = acc[t][r] * SCALE_;
            if (key > qq) s = MINV_;
            s_s[quad * 4 + r][key] = s + mval;
        }
    }
    __syncthreads();

    int g = tid >> 4, lg = tid & 15;
    float vals[16];
    float mx = MINV_;
    #pragma unroll
    for (int i = 0; i < 16; i++) { vals[i] = s_s[g][lg + 16 * i]; mx = fmaxf(mx, vals[i]); }
    #pragma unroll
    for (int m = 1; m < 16; m <<= 1) mx = fmaxf(mx, __shfl_xor(mx, m, 64));
    float l = 0.f;
    #pragma unroll
    for (int i = 0; i < 16; i++) { float e = __expf(vals[i] - mx); l += e; p_s[g][lg + 16 * i] = (bf16)e; }
    #pragma unroll
    for (int m = 1; m < 16; m <<= 1) l += __shfl_xor(l, m, 64);
    if (lg == 0) inv_l[g] = 1.0f / l;
    __syncthreads();

    f32x4 o[2];
    o[0] = (f32x4){0.f, 0.f, 0.f, 0.f}; o[1] = (f32x4){0.f, 0.f, 0.f, 0.f};
    #pragma unroll
    for (int ks = 0; ks < 8; ks++) {
        bf16x8 pa = LD8(&p_s[l16][ks * 32 + quad * 8]);
        #pragma unroll
        for (int t = 0; t < 2; t++) {
            int d = wv * 32 + t * 16 + l16;
            bf16x8 vb = LD8(vmT + (size_t)(b * 128 + d) * 2048 + ks * 32 + quad * 8);
            o[t] = mfma16(pa, vb, o[t]);
        }
    }
    #pragma unroll
    for (int t = 0; t < 2; t++) {
        int d = wv * 32 + t * 16 + l16;
        #pragma unroll
        for (int r = 0; r < 4; r++) {
            int qq = q0 + quad * 4 + r;
            attn[(size_t)(b * 2048 + qq) * 2048 + h * 128 + d] = (bf16)(o[t][r] * inv_l[quad * 4 + r]);
        }
    }
}

// ---------------- attention steps v3: barrier-free, wave-autonomous, pretiled frags ----------------
// Wave owns 1 step x 16 heads. Chunks of 64 keys: chunk 32 = global, then 64-aligned window chunks
// c0..min(c0+4,31) with per-lane range masking. All B-frag loads are coalesced 1KB.
#define PSTRIDE 88
__global__ __launch_bounds__(256) void attn_steps3_kernel(const bf16* __restrict__ C1, const bf16* __restrict__ KF,
                                                          const bf16* __restrict__ VF, const float* __restrict__ mask,
                                                          const int* __restrict__ gidx, bf16* __restrict__ attn)
{
    const int sb = blockIdx.x, b = blockIdx.y;
    const int tid = threadIdx.x, wv = tid >> 6, lane = tid & 63, quad = lane >> 4, l16 = lane & 15;
    const int step = sb * 4 + wv, p = 256 + step;

    __shared__ __align__(16) bf16 Ps[4 * 16 * PSTRIDE];
    bf16* Pw = &Ps[wv * (16 * PSTRIDE)];

    // Q A-fragments: A[m=head=l16][k=quad*8+j]
    bf16x8 af[4];
    const bf16* qrow = C1 + (size_t)(b * 2048 + p) * 2304;
    #pragma unroll
    for (int ks = 0; ks < 4; ks++) af[ks] = LD8(qrow + l16 * 128 + ks * 32 + quad * 8);

    // global-key indices for validity (per n-tile t: key = t*16+l16)
    int gix[4];
    #pragma unroll
    for (int t = 0; t < 4; t++) gix[t] = gidx[b * 64 + t * 16 + l16];

    f32x4 m_run = (f32x4){MINV_, MINV_, MINV_, MINV_};
    f32x4 l_run = (f32x4){0.f, 0.f, 0.f, 0.f};
    f32x4 O[8];
    #pragma unroll
    for (int dt = 0; dt < 8; dt++) O[dt] = (f32x4){0.f, 0.f, 0.f, 0.f};

    const int c0 = (step + 1) >> 6;

    for (int iter = 0; iter < 6; iter++) {
        int c;
        bool isGlob = (iter == 0);
        if (isGlob) c = 32;
        else { c = c0 + iter - 1; if (c > 31) break; }

        const bf16* KFc = KF + ((size_t)(b * 33 + c) * 16) * 512;
        const bf16* VFc = VF + ((size_t)(b * 33 + c) * 16) * 512;

        // ---- QK^T: 4 n-tiles x 4 k-steps, coalesced frag loads ----
        f32x4 acc[4];
        #pragma unroll
        for (int t = 0; t < 4; t++) acc[t] = (f32x4){0.f, 0.f, 0.f, 0.f};
        #pragma unroll
        for (int t = 0; t < 4; t++)
            #pragma unroll
            for (int ks = 0; ks < 4; ks++)
                acc[t] = mfma16(af[ks], LD8(KFc + (size_t)(t * 4 + ks) * 512 + lane * 8), acc[t]);

        // ---- mask + scale ----
        float sv[4][4];
        bool vld[4];
        #pragma unroll
        for (int t = 0; t < 4; t++) {
            float addv = 0.f;
            if (isGlob) vld[t] = gix[t] < step;
            else {
                int pos = c * 64 + t * 16 + l16;
                vld[t] = (unsigned)(pos - step - 1) < 256u;
                addv = mask[b * 2048 + pos];
            }
            #pragma unroll
            for (int r = 0; r < 4; r++) sv[t][r] = vld[t] ? (acc[t][r] * SCALE_ + addv) : MINV_;
        }

        // ---- online softmax update (row = head = quad*4+r, reduce over quad's 16 lanes) ----
        f32x4 cm;
        #pragma unroll
        for (int r = 0; r < 4; r++) cm[r] = fmaxf(fmaxf(sv[0][r], sv[1][r]), fmaxf(sv[2][r], sv[3][r]));
        #pragma unroll
        for (int ms = 1; ms < 16; ms <<= 1)
            #pragma unroll
            for (int r = 0; r < 4; r++) cm[r] = fmaxf(cm[r], __shfl_xor(cm[r], ms, 64));

        f32x4 nm, alpha;
        #pragma unroll
        for (int r = 0; r < 4; r++) { nm[r] = fmaxf(m_run[r], cm[r]); alpha[r] = __expf(m_run[r] - nm[r]); }

        float pv[4][4];
        f32x4 cs = (f32x4){0.f, 0.f, 0.f, 0.f};
        #pragma unroll
        for (int t = 0; t < 4; t++)
            #pragma unroll
            for (int r = 0; r < 4; r++) {
                pv[t][r] = vld[t] ? __expf(sv[t][r] - nm[r]) : 0.f;
                cs[r] += pv[t][r];
            }
        #pragma unroll
        for (int ms = 1; ms < 16; ms <<= 1)
            #pragma unroll
            for (int r = 0; r < 4; r++) cs[r] += __shfl_xor(cs[r], ms, 64);

        m_run = nm;
        #pragma unroll
        for (int r = 0; r < 4; r++) l_run[r] = l_run[r] * alpha[r] + cs[r];
        #pragma unroll
        for (int dt = 0; dt < 8; dt++)
            #pragma unroll
            for (int r = 0; r < 4; r++) O[dt][r] *= alpha[r];

        // ---- P: C-layout -> per-wave LDS -> A-layout (same-wave DS order, no barrier) ----
        #pragma unroll
        for (int t = 0; t < 4; t++)
            #pragma unroll
            for (int r = 0; r < 4; r++)
                Pw[(quad * 4 + r) * PSTRIDE + t * 16 + l16] = (bf16)pv[t][r];
        bf16x8 pa0 = LD8(&Pw[l16 * PSTRIDE + quad * 8]);
        bf16x8 pa1 = LD8(&Pw[l16 * PSTRIDE + 32 + quad * 8]);

        // ---- PV: 8 d-tiles x 2 k-steps, coalesced frag loads ----
        #pragma unroll
        for (int dt = 0; dt < 8; dt++) {
            O[dt] = mfma16(pa0, LD8(VFc + (size_t)(dt * 2 + 0) * 512 + lane * 8), O[dt]);
            O[dt] = mfma16(pa1, LD8(VFc + (size_t)(dt * 2 + 1) * 512 + lane * 8), O[dt]);
        }
    }

    // ---- epilogue ----
    f32x4 invl;
    #pragma unroll
    for (int r = 0; r < 4; r++) invl[r] = 1.0f / l_run[r];
    #pragma unroll
    for (int dt = 0; dt < 8; dt++)
        #pragma unroll
        for (int r = 0; r < 4; r++) {
            int h = quad * 4 + r;
            attn[(size_t)(b * 2048 + p) * 2048 + h * 128 + dt * 16 + l16] = (bf16)(O[dt][r] * invl[r]);
        }
}

// ---------------- launch ----------------
extern "C" void kernel_launch(void* const* d_in, const int* in_sizes, int n_in,
                              void* d_out, int out_size, void* d_ws, size_t ws_size,
                              hipStream_t stream)
{
    const float* hidden = (const float*)d_in[0];
    const float* amask  = (const float*)d_in[1];
    const int*   gidx   = (const int*)d_in[2];
    const float* Wqkv   = (const float*)d_in[3];
    const float* bqkv   = (const float*)d_in[4];
    const float* Wo     = (const float*)d_in[5];
    const float* bo     = (const float*)d_in[6];

    char* ws = (char*)d_ws;
    size_t off = 0;
    auto take = [&](size_t bytes) -> char* {
        char* p = ws + off;
        off = (off + bytes + 255) & ~(size_t)255;
        return p;
    };
    bf16*  A16   = (bf16*)take(4096ull * 2048 * 2);   // hidden, bf16
    bf16*  BT1   = (bf16*)take(2304ull * 2048 * 2);   // [q cols | k-avg | v-avg]^T
    bf16*  BT2   = (bf16*)take(2048ull * 2048 * 2);   // Wo^T
    bf16*  C1    = (bf16*)take(4096ull * 2304 * 2);   // q(2048) | k_mean(128) | v_mean(128)
    bf16*  vmT   = (bf16*)take(2ull * 128 * 2048 * 2);
    bf16*  KF    = (bf16*)take(2ull * 33 * 16 * 512 * 2);
    bf16*  VF    = (bf16*)take(2ull * 33 * 16 * 512 * 2);
    bf16*  attnb = (bf16*)take(4096ull * 2048 * 2);
    float* bias1 = (float*)take(2304 * 4);

    cast_hidden_kernel<<<8192, 256, 0, stream>>>(hidden, A16);
    transpose_cast_kernel<<<dim3(64, 64), 256, 0, stream>>>(Wqkv, BT1, 6144, 1);
    bt1_kv_kernel<<<dim3(8, 256), 256, 0, stream>>>(Wqkv, BT1);
    bias1_kernel<<<9, 256, 0, stream>>>(bqkv, bias1);
    transpose_cast_kernel<<<dim3(64, 64), 256, 0, stream>>>(Wo, BT2, 2048, 0);

    gemm_kernel<1><<<dim3(18, 32), 256, 0, stream>>>(A16, BT1, bias1, (void*)C1, 4096, 2304, 2048);

    rotary_kernel<<<4096, 320, 0, stream>>>(C1);
    build_vmT_kernel<<<dim3(64, 4, 2), 256, 0, stream>>>(C1, vmT);
    pretile_win_kernel<<<dim3(32, 2), 256, 0, stream>>>(C1, vmT, KF, VF);
    pretile_glob_kernel<<<2, 256, 0, stream>>>(C1, vmT, gidx, KF, VF);

    attn0_kernel<<<dim3(16, 16, 2), 256, 0, stream>>>(C1, vmT, amask, attnb);
    attn_steps3_kernel<<<dim3(448, 2), 256, 0, stream>>>(C1, KF, VF, amask, gidx, attnb);

    gemm_kernel<0><<<dim3(16, 32), 256, 0, stream>>>(attnb, BT2, bo, d_out, 4096, 2048, 2048);

    (void)in_sizes; (void)n_in; (void)out_size; (void)ws_size;
}

// Round 4
// 327.195 us; speedup vs baseline: 1.5670x; 1.1984x over previous
//
#include <hip/hip_runtime.h>
#include <math.h>

#define SCALE_ 0.08838834764831845f   // 1/sqrt(128)
#define MINV_  (-3.4028234663852886e38f)

typedef __bf16 bf16;
typedef bf16  bf16x4 __attribute__((ext_vector_type(4)));
typedef bf16  bf16x8 __attribute__((ext_vector_type(8)));
typedef float f32x4  __attribute__((ext_vector_type(4)));
typedef float float4v __attribute__((ext_vector_type(4)));

#define LD8(p) (*(const bf16x8*)(p))

__device__ __forceinline__ f32x4 mfma16(bf16x8 a, bf16x8 b, f32x4 c) {
    return __builtin_amdgcn_mfma_f32_16x16x32_bf16(a, b, c, 0, 0, 0);
}

typedef const __attribute__((address_space(1))) void* gas_t;
typedef __attribute__((address_space(3))) void* sas_t;
__device__ __forceinline__ void gload_lds16(const void* g, void* l) {
    __builtin_amdgcn_global_load_lds((gas_t)g, (sas_t)l, 16, 0, 0);
}

// ---------------- prep kernels ----------------

__global__ __launch_bounds__(256) void cast_hidden_kernel(const float* __restrict__ X, bf16* __restrict__ Y)
{
    int i = (blockIdx.x * 256 + threadIdx.x) * 4;
    float4v v = *(const float4v*)(X + i);
    bf16x4 o; o.x = (bf16)v.x; o.y = (bf16)v.y; o.z = (bf16)v.z; o.w = (bf16)v.w;
    *(bf16x4*)(Y + i) = o;
}

// BT[n][k] = W[k][src(n)]; qmap: src = (n>>7)*384 + (n&127) (q columns of Wqkv), else src=n (Wo)
__global__ __launch_bounds__(256) void transpose_cast_kernel(const float* __restrict__ W, bf16* __restrict__ BT,
                                                             int srcStride, int qmap)
{
    __shared__ float tile[32][33];
    int k0 = blockIdx.x * 32, n0 = blockIdx.y * 32;
    int c = threadIdx.x & 31, r = threadIdx.x >> 5;   // r in 0..7
    int n = n0 + c;
    int src = qmap ? ((n >> 7) * 384 + (n & 127)) : n;
    #pragma unroll
    for (int rr = 0; rr < 32; rr += 8)
        tile[r + rr][c] = W[(size_t)(k0 + r + rr) * srcStride + src];
    __syncthreads();
    #pragma unroll
    for (int rr = 0; rr < 32; rr += 8)
        BT[(size_t)(n0 + r + rr) * 2048 + k0 + c] = (bf16)tile[c][r + rr];
}

// rows 2048..2303 of BT1: head-averaged k/v weight columns. Coalesced: thread=j, 1KB row segments.
__global__ __launch_bounds__(256) void bt1_kv_kernel(const float* __restrict__ Wqkv, bf16* __restrict__ BT1)
{
    int k0 = blockIdx.x * 16;
    int j = threadIdx.x;            // 0..255
    float acc[16];
    #pragma unroll
    for (int k = 0; k < 16; k++) acc[k] = 0.f;
    for (int h = 0; h < 16; h++) {
        #pragma unroll
        for (int k = 0; k < 16; k++)
            acc[k] += Wqkv[(size_t)(k0 + k) * 6144 + h * 384 + 128 + j];
    }
    #pragma unroll
    for (int k = 0; k < 16; k++)
        BT1[(size_t)(2048 + j) * 2048 + k0 + k] = (bf16)(acc[k] * 0.0625f);
}

__global__ void bias1_kernel(const float* __restrict__ bqkv, float* __restrict__ bias1)
{
    int c = blockIdx.x * 256 + threadIdx.x;
    if (c >= 2304) return;
    if (c < 2048) bias1[c] = bqkv[(c >> 7) * 384 + (c & 127)];
    else {
        int j = c - 2048; float s = 0.f;
        for (int h = 0; h < 16; h++) s += bqkv[h * 384 + 128 + j];
        bias1[c] = s * 0.0625f;
    }
}

// ---------------- GEMM (m97 structure): C[m][n] = A[m][:] . BT[n][:] + bias[n] ----------------
// 128x128 tile, BK=64, global_load_lds width-16 staging with XOR swizzle on the gather side:
// LDS chunk (row, cp) holds global chunk c = cp ^ (row&7)  -> ds_read_b128 is conflict-free.
template<int OUT_BF16>
__global__ __launch_bounds__(256) void gemm_kernel(const bf16* __restrict__ A, const bf16* __restrict__ BT,
                                                   const float* __restrict__ bias, void* __restrict__ Cout,
                                                   int M, int N, int K)
{
    __shared__ __align__(16) bf16 As[128 * 64];
    __shared__ __align__(16) bf16 Bs[128 * 64];
    const int tid  = threadIdx.x;
    const int wv   = tid >> 6, lane = tid & 63, quad = lane >> 4, l16 = lane & 15;
    const int wrow = wv >> 1, wcol = wv & 1;
    const int m0 = blockIdx.y * 128, n0 = blockIdx.x * 128;

    // staging geometry: issue j of wave wv covers flat chunk ids (wv*4+j)*64 + lane
    int rowS[4], colS[4];
    #pragma unroll
    for (int j = 0; j < 4; j++) {
        int flat = (wv * 4 + j) * 64 + lane;
        int row = flat >> 3, cp = flat & 7;
        rowS[j] = row;
        colS[j] = (cp ^ (row & 7)) * 8;
    }

    f32x4 acc[4][4];
    #pragma unroll
    for (int i = 0; i < 4; i++)
        #pragma unroll
        for (int j = 0; j < 4; j++) acc[i][j] = (f32x4){0.f, 0.f, 0.f, 0.f};

    for (int kk = 0; kk < K; kk += 64) {
        __syncthreads();   // previous iter's frag reads done
        #pragma unroll
        for (int j = 0; j < 4; j++) {
            gload_lds16(A  + (size_t)(m0 + rowS[j]) * K + kk + colS[j], &As[(wv * 4 + j) * 512]);
            gload_lds16(BT + (size_t)(n0 + rowS[j]) * K + kk + colS[j], &Bs[(wv * 4 + j) * 512]);
        }
        __syncthreads();   // staging complete (vmcnt(0) drained by barrier)

        bf16x8 af[4][2], bfr[4][2];
        #pragma unroll
        for (int i = 0; i < 4; i++) {
            int row = wrow * 64 + i * 16 + l16;
            #pragma unroll
            for (int ks = 0; ks < 2; ks++) {
                int lc = ks * 4 + quad;
                af[i][ks] = LD8(&As[row * 64 + ((lc ^ (row & 7)) * 8)]);
            }
        }
        #pragma unroll
        for (int i = 0; i < 4; i++) {
            int row = wcol * 64 + i * 16 + l16;
            #pragma unroll
            for (int ks = 0; ks < 2; ks++) {
                int lc = ks * 4 + quad;
                bfr[i][ks] = LD8(&Bs[row * 64 + ((lc ^ (row & 7)) * 8)]);
            }
        }
        #pragma unroll
        for (int ks = 0; ks < 2; ks++)
            #pragma unroll
            for (int i = 0; i < 4; i++)
                #pragma unroll
                for (int j = 0; j < 4; j++)
                    acc[i][j] = mfma16(af[i][ks], bfr[j][ks], acc[i][j]);
    }

    #pragma unroll
    for (int i = 0; i < 4; i++) {
        #pragma unroll
        for (int j = 0; j < 4; j++) {
            int n = n0 + wcol * 64 + j * 16 + l16;
            float bn = bias[n];
            #pragma unroll
            for (int r = 0; r < 4; r++) {
                int m = m0 + wrow * 64 + i * 16 + quad * 4 + r;
                float v = acc[i][j][r] + bn;
                if (OUT_BF16) ((bf16*)Cout)[(size_t)m * N + n] = (bf16)v;
                else          ((float*)Cout)[(size_t)m * N + n] = v;
            }
        }
    }
}

// ---------------- rotary (in-place on C1 bf16): q (16 heads) + k_mean, first 32 dims ----------------
__global__ __launch_bounds__(320) void rotary_kernel(bf16* __restrict__ C1)
{
    int row = blockIdx.x;          // b*2048 + s
    int s = row & 2047;
    int t = threadIdx.x;
    if (t >= 272) return;          // 17 groups (16 q heads + k_mean) x 16 dim-pairs
    int g = t >> 4, dd = t & 15;
    bf16* ptr = C1 + (size_t)row * 2304 + (g < 16 ? g * 128 : 2048);
    float x0 = (float)ptr[dd], x1 = (float)ptr[dd + 16];
    const float L = 0.575646273248511f;  // ln(10000)/16
    float inv = expf(-L * (float)dd);
    float ang = (float)s * inv;
    float c = cosf(ang), si = sinf(ang);
    ptr[dd]      = (bf16)(x0 * c - x1 * si);
    ptr[dd + 16] = (bf16)(x1 * c + x0 * si);
}

// ---------------- vmT[b][d][s] = v_mean transposed ----------------
__global__ __launch_bounds__(256) void build_vmT_kernel(const bf16* __restrict__ C1, bf16* __restrict__ vmT)
{
    __shared__ float tile[32][33];
    int b = blockIdx.z;
    int s0 = blockIdx.x * 32, d0 = blockIdx.y * 32;
    int c = threadIdx.x & 31, r = threadIdx.x >> 5;
    #pragma unroll
    for (int rr = 0; rr < 32; rr += 8)
        tile[r + rr][c] = (float)C1[(size_t)(b * 2048 + s0 + r + rr) * 2304 + 2176 + d0 + c];
    __syncthreads();
    #pragma unroll
    for (int rr = 0; rr < 32; rr += 8)
        vmT[(size_t)(b * 128 + d0 + r + rr) * 2048 + s0 + c] = (bf16)tile[c][r + rr];
}

// ---------------- pretile K/V into MFMA fragment order at 64-aligned key chunks ----------------
__global__ __launch_bounds__(256) void pretile_win_kernel(const bf16* __restrict__ C1, const bf16* __restrict__ vmT,
                                                          bf16* __restrict__ KF, bf16* __restrict__ VF)
{
    int c = blockIdx.x, b = blockIdx.y;
    for (int i = 0; i < 8; i++) {
        int sid = threadIdx.x + i * 256;     // 0..2047
        int lane = sid & 63, fi = (sid >> 6) & 15;
        int l16 = lane & 15, quad = lane >> 4;
        if (sid < 1024) {
            int t = fi >> 2, ks = fi & 3;
            const bf16* src = C1 + (size_t)(b * 2048 + c * 64 + t * 16 + l16) * 2304 + 2048 + ks * 32 + quad * 8;
            *(bf16x8*)&KF[((size_t)(b * 33 + c) * 16 + fi) * 512 + lane * 8] = LD8(src);
        } else {
            int dt = fi >> 1, ks2 = fi & 1;
            const bf16* src = vmT + (size_t)(b * 128 + dt * 16 + l16) * 2048 + c * 64 + ks2 * 32 + quad * 8;
            *(bf16x8*)&VF[((size_t)(b * 33 + c) * 16 + fi) * 512 + lane * 8] = LD8(src);
        }
    }
}

// chunk 32 = 64 gathered global keys
__global__ __launch_bounds__(256) void pretile_glob_kernel(const bf16* __restrict__ C1, const bf16* __restrict__ vmT,
                                                           const int* __restrict__ gidx,
                                                           bf16* __restrict__ KF, bf16* __restrict__ VF)
{
    int b = blockIdx.x;
    for (int i = 0; i < 8; i++) {
        int sid = threadIdx.x + i * 256;
        int lane = sid & 63, fi = (sid >> 6) & 15;
        int l16 = lane & 15, quad = lane >> 4;
        if (sid < 1024) {
            int t = fi >> 2, ks = fi & 3;
            int pos = gidx[b * 64 + t * 16 + l16];
            const bf16* src = C1 + (size_t)(b * 2048 + pos) * 2304 + 2048 + ks * 32 + quad * 8;
            *(bf16x8*)&KF[((size_t)(b * 33 + 32) * 16 + fi) * 512 + lane * 8] = LD8(src);
        } else {
            int dt = fi >> 1, ks2 = fi & 1;
            int d = dt * 16 + l16;
            bf16 tmp[8];
            #pragma unroll
            for (int j = 0; j < 8; j++) {
                int pos = gidx[b * 64 + ks2 * 32 + quad * 8 + j];
                tmp[j] = vmT[(size_t)(b * 128 + d) * 2048 + pos];
            }
            #pragma unroll
            for (int j = 0; j < 8; j++)
                VF[((size_t)(b * 33 + 32) * 16 + fi) * 512 + lane * 8 + j] = tmp[j];
        }
    }
}

#define PSTRIDE 88

// ---------------- attention, first WIN=256 queries (causal): wave-autonomous, pretiled frags ----------------
// Block (bx, h, b); wave wv owns qtile = bx*4+wv (16 queries), head h. Chunks 0..bx of KF/VF.
__global__ __launch_bounds__(256) void attn0_kernel(const bf16* __restrict__ C1, const bf16* __restrict__ KF,
                                                    const bf16* __restrict__ VF, const float* __restrict__ mask,
                                                    bf16* __restrict__ attn)
{
    const int bx = blockIdx.x, h = blockIdx.y, b = blockIdx.z;
    const int tid = threadIdx.x, wv = tid >> 6, lane = tid & 63, quad = lane >> 4, l16 = lane & 15;
    const int q0 = (bx * 4 + wv) * 16;

    __shared__ __align__(16) bf16 Ps[4 * 16 * PSTRIDE];
    bf16* Pw = &Ps[wv * (16 * PSTRIDE)];

    // Q A-fragments: A[m=query=l16][k]
    bf16x8 af[4];
    const bf16* qbase = C1 + (size_t)(b * 2048 + q0 + l16) * 2304 + h * 128;
    #pragma unroll
    for (int ks = 0; ks < 4; ks++) af[ks] = LD8(qbase + ks * 32 + quad * 8);

    f32x4 m_run = (f32x4){MINV_, MINV_, MINV_, MINV_};
    f32x4 l_run = (f32x4){0.f, 0.f, 0.f, 0.f};
    f32x4 O[8];
    #pragma unroll
    for (int dt = 0; dt < 8; dt++) O[dt] = (f32x4){0.f, 0.f, 0.f, 0.f};

    for (int c = 0; c <= bx; c++) {
        const bf16* KFc = KF + ((size_t)(b * 33 + c) * 16) * 512;
        const bf16* VFc = VF + ((size_t)(b * 33 + c) * 16) * 512;

        f32x4 acc[4];
        #pragma unroll
        for (int t = 0; t < 4; t++) acc[t] = (f32x4){0.f, 0.f, 0.f, 0.f};
        #pragma unroll
        for (int t = 0; t < 4; t++)
            #pragma unroll
            for (int ks = 0; ks < 4; ks++)
                acc[t] = mfma16(af[ks], LD8(KFc + (size_t)(t * 4 + ks) * 512 + lane * 8), acc[t]);

        // causal mask per (t, r): q = q0+quad*4+r, key = c*64 + t*16 + l16
        float sv[4][4];
        #pragma unroll
        for (int t = 0; t < 4; t++) {
            int key = c * 64 + t * 16 + l16;
            float addv = mask[b * 2048 + key];
            #pragma unroll
            for (int r = 0; r < 4; r++) {
                int q = q0 + quad * 4 + r;
                sv[t][r] = (key <= q) ? (acc[t][r] * SCALE_ + addv) : MINV_;
            }
        }

        f32x4 cm;
        #pragma unroll
        for (int r = 0; r < 4; r++) cm[r] = fmaxf(fmaxf(sv[0][r], sv[1][r]), fmaxf(sv[2][r], sv[3][r]));
        #pragma unroll
        for (int ms = 1; ms < 16; ms <<= 1)
            #pragma unroll
            for (int r = 0; r < 4; r++) cm[r] = fmaxf(cm[r], __shfl_xor(cm[r], ms, 64));

        f32x4 nm, alpha;
        #pragma unroll
        for (int r = 0; r < 4; r++) { nm[r] = fmaxf(m_run[r], cm[r]); alpha[r] = __expf(m_run[r] - nm[r]); }

        float pv[4][4];
        f32x4 cs = (f32x4){0.f, 0.f, 0.f, 0.f};
        #pragma unroll
        for (int t = 0; t < 4; t++)
            #pragma unroll
            for (int r = 0; r < 4; r++) {
                pv[t][r] = __expf(sv[t][r] - nm[r]);   // MINV_ underflows to 0
                cs[r] += pv[t][r];
            }
        #pragma unroll
        for (int ms = 1; ms < 16; ms <<= 1)
            #pragma unroll
            for (int r = 0; r < 4; r++) cs[r] += __shfl_xor(cs[r], ms, 64);

        m_run = nm;
        #pragma unroll
        for (int r = 0; r < 4; r++) l_run[r] = l_run[r] * alpha[r] + cs[r];
        #pragma unroll
        for (int dt = 0; dt < 8; dt++)
            #pragma unroll
            for (int r = 0; r < 4; r++) O[dt][r] *= alpha[r];

        #pragma unroll
        for (int t = 0; t < 4; t++)
            #pragma unroll
            for (int r = 0; r < 4; r++)
                Pw[(quad * 4 + r) * PSTRIDE + t * 16 + l16] = (bf16)pv[t][r];
        bf16x8 pa0 = LD8(&Pw[l16 * PSTRIDE + quad * 8]);
        bf16x8 pa1 = LD8(&Pw[l16 * PSTRIDE + 32 + quad * 8]);

        #pragma unroll
        for (int dt = 0; dt < 8; dt++) {
            O[dt] = mfma16(pa0, LD8(VFc + (size_t)(dt * 2 + 0) * 512 + lane * 8), O[dt]);
            O[dt] = mfma16(pa1, LD8(VFc + (size_t)(dt * 2 + 1) * 512 + lane * 8), O[dt]);
        }
    }

    f32x4 invl;
    #pragma unroll
    for (int r = 0; r < 4; r++) invl[r] = 1.0f / l_run[r];
    #pragma unroll
    for (int dt = 0; dt < 8; dt++)
        #pragma unroll
        for (int r = 0; r < 4; r++) {
            int q = q0 + quad * 4 + r;
            attn[(size_t)(b * 2048 + q) * 2048 + h * 128 + dt * 16 + l16] = (bf16)(O[dt][r] * invl[r]);
        }
}

// ---------------- attention steps v3: barrier-free, wave-autonomous, pretiled frags ----------------
__global__ __launch_bounds__(256) void attn_steps3_kernel(const bf16* __restrict__ C1, const bf16* __restrict__ KF,
                                                          const bf16* __restrict__ VF, const float* __restrict__ mask,
                                                          const int* __restrict__ gidx, bf16* __restrict__ attn)
{
    const int sb = blockIdx.x, b = blockIdx.y;
    const int tid = threadIdx.x, wv = tid >> 6, lane = tid & 63, quad = lane >> 4, l16 = lane & 15;
    const int step = sb * 4 + wv, p = 256 + step;

    __shared__ __align__(16) bf16 Ps[4 * 16 * PSTRIDE];
    bf16* Pw = &Ps[wv * (16 * PSTRIDE)];

    bf16x8 af[4];
    const bf16* qrow = C1 + (size_t)(b * 2048 + p) * 2304;
    #pragma unroll
    for (int ks = 0; ks < 4; ks++) af[ks] = LD8(qrow + l16 * 128 + ks * 32 + quad * 8);

    int gix[4];
    #pragma unroll
    for (int t = 0; t < 4; t++) gix[t] = gidx[b * 64 + t * 16 + l16];

    f32x4 m_run = (f32x4){MINV_, MINV_, MINV_, MINV_};
    f32x4 l_run = (f32x4){0.f, 0.f, 0.f, 0.f};
    f32x4 O[8];
    #pragma unroll
    for (int dt = 0; dt < 8; dt++) O[dt] = (f32x4){0.f, 0.f, 0.f, 0.f};

    const int c0 = (step + 1) >> 6;

    for (int iter = 0; iter < 6; iter++) {
        int c;
        bool isGlob = (iter == 0);
        if (isGlob) c = 32;
        else { c = c0 + iter - 1; if (c > 31) break; }

        const bf16* KFc = KF + ((size_t)(b * 33 + c) * 16) * 512;
        const bf16* VFc = VF + ((size_t)(b * 33 + c) * 16) * 512;

        f32x4 acc[4];
        #pragma unroll
        for (int t = 0; t < 4; t++) acc[t] = (f32x4){0.f, 0.f, 0.f, 0.f};
        #pragma unroll
        for (int t = 0; t < 4; t++)
            #pragma unroll
            for (int ks = 0; ks < 4; ks++)
                acc[t] = mfma16(af[ks], LD8(KFc + (size_t)(t * 4 + ks) * 512 + lane * 8), acc[t]);

        float sv[4][4];
        bool vld[4];
        #pragma unroll
        for (int t = 0; t < 4; t++) {
            float addv = 0.f;
            if (isGlob) vld[t] = gix[t] < step;
            else {
                int pos = c * 64 + t * 16 + l16;
                vld[t] = (unsigned)(pos - step - 1) < 256u;
                addv = mask[b * 2048 + pos];
            }
            #pragma unroll
            for (int r = 0; r < 4; r++) sv[t][r] = vld[t] ? (acc[t][r] * SCALE_ + addv) : MINV_;
        }

        f32x4 cm;
        #pragma unroll
        for (int r = 0; r < 4; r++) cm[r] = fmaxf(fmaxf(sv[0][r], sv[1][r]), fmaxf(sv[2][r], sv[3][r]));
        #pragma unroll
        for (int ms = 1; ms < 16; ms <<= 1)
            #pragma unroll
            for (int r = 0; r < 4; r++) cm[r] = fmaxf(cm[r], __shfl_xor(cm[r], ms, 64));

        f32x4 nm, alpha;
        #pragma unroll
        for (int r = 0; r < 4; r++) { nm[r] = fmaxf(m_run[r], cm[r]); alpha[r] = __expf(m_run[r] - nm[r]); }

        float pv[4][4];
        f32x4 cs = (f32x4){0.f, 0.f, 0.f, 0.f};
        #pragma unroll
        for (int t = 0; t < 4; t++)
            #pragma unroll
            for (int r = 0; r < 4; r++) {
                pv[t][r] = vld[t] ? __expf(sv[t][r] - nm[r]) : 0.f;
                cs[r] += pv[t][r];
            }
        #pragma unroll
        for (int ms = 1; ms < 16; ms <<= 1)
            #pragma unroll
            for (int r = 0; r < 4; r++) cs[r] += __shfl_xor(cs[r], ms, 64);

        m_run = nm;
        #pragma unroll
        for (int r = 0; r < 4; r++) l_run[r] = l_run[r] * alpha[r] + cs[r];
        #pragma unroll
        for (int dt = 0; dt < 8; dt++)
            #pragma unroll
            for (int r = 0; r < 4; r++) O[dt][r] *= alpha[r];

        #pragma unroll
        for (int t = 0; t < 4; t++)
            #pragma unroll
            for (int r = 0; r < 4; r++)
                Pw[(quad * 4 + r) * PSTRIDE + t * 16 + l16] = (bf16)pv[t][r];
        bf16x8 pa0 = LD8(&Pw[l16 * PSTRIDE + quad * 8]);
        bf16x8 pa1 = LD8(&Pw[l16 * PSTRIDE + 32 + quad * 8]);

        #pragma unroll
        for (int dt = 0; dt < 8; dt++) {
            O[dt] = mfma16(pa0, LD8(VFc + (size_t)(dt * 2 + 0) * 512 + lane * 8), O[dt]);
            O[dt] = mfma16(pa1, LD8(VFc + (size_t)(dt * 2 + 1) * 512 + lane * 8), O[dt]);
        }
    }

    f32x4 invl;
    #pragma unroll
    for (int r = 0; r < 4; r++) invl[r] = 1.0f / l_run[r];
    #pragma unroll
    for (int dt = 0; dt < 8; dt++)
        #pragma unroll
        for (int r = 0; r < 4; r++) {
            int h = quad * 4 + r;
            attn[(size_t)(b * 2048 + p) * 2048 + h * 128 + dt * 16 + l16] = (bf16)(O[dt][r] * invl[r]);
        }
}

// ---------------- launch ----------------
extern "C" void kernel_launch(void* const* d_in, const int* in_sizes, int n_in,
                              void* d_out, int out_size, void* d_ws, size_t ws_size,
                              hipStream_t stream)
{
    const float* hidden = (const float*)d_in[0];
    const float* amask  = (const float*)d_in[1];
    const int*   gidx   = (const int*)d_in[2];
    const float* Wqkv   = (const float*)d_in[3];
    const float* bqkv   = (const float*)d_in[4];
    const float* Wo     = (const float*)d_in[5];
    const float* bo     = (const float*)d_in[6];

    char* ws = (char*)d_ws;
    size_t off = 0;
    auto take = [&](size_t bytes) -> char* {
        char* p = ws + off;
        off = (off + bytes + 255) & ~(size_t)255;
        return p;
    };
    bf16*  A16   = (bf16*)take(4096ull * 2048 * 2);   // hidden, bf16
    bf16*  BT1   = (bf16*)take(2304ull * 2048 * 2);   // [q cols | k-avg | v-avg]^T
    bf16*  BT2   = (bf16*)take(2048ull * 2048 * 2);   // Wo^T
    bf16*  C1    = (bf16*)take(4096ull * 2304 * 2);   // q(2048) | k_mean(128) | v_mean(128)
    bf16*  vmT   = (bf16*)take(2ull * 128 * 2048 * 2);
    bf16*  KF    = (bf16*)take(2ull * 33 * 16 * 512 * 2);
    bf16*  VF    = (bf16*)take(2ull * 33 * 16 * 512 * 2);
    bf16*  attnb = (bf16*)take(4096ull * 2048 * 2);
    float* bias1 = (float*)take(2304 * 4);

    cast_hidden_kernel<<<8192, 256, 0, stream>>>(hidden, A16);
    transpose_cast_kernel<<<dim3(64, 64), 256, 0, stream>>>(Wqkv, BT1, 6144, 1);
    bt1_kv_kernel<<<128, 256, 0, stream>>>(Wqkv, BT1);
    bias1_kernel<<<9, 256, 0, stream>>>(bqkv, bias1);
    transpose_cast_kernel<<<dim3(64, 64), 256, 0, stream>>>(Wo, BT2, 2048, 0);

    gemm_kernel<1><<<dim3(18, 32), 256, 0, stream>>>(A16, BT1, bias1, (void*)C1, 4096, 2304, 2048);

    rotary_kernel<<<4096, 320, 0, stream>>>(C1);
    build_vmT_kernel<<<dim3(64, 4, 2), 256, 0, stream>>>(C1, vmT);
    pretile_win_kernel<<<dim3(32, 2), 256, 0, stream>>>(C1, vmT, KF, VF);
    pretile_glob_kernel<<<2, 256, 0, stream>>>(C1, vmT, gidx, KF, VF);

    attn0_kernel<<<dim3(4, 16, 2), 256, 0, stream>>>(C1, KF, VF, amask, attnb);
    attn_steps3_kernel<<<dim3(448, 2), 256, 0, stream>>>(C1, KF, VF, amask, gidx, attnb);

    gemm_kernel<0><<<dim3(16, 32), 256, 0, stream>>>(attnb, BT2, bo, d_out, 4096, 2048, 2048);

    (void)in_sizes; (void)n_in; (void)out_size; (void)ws_size;
}

// Round 5
// 320.974 us; speedup vs baseline: 1.5974x; 1.0194x over previous
//
#include <hip/hip_runtime.h>
#include <math.h>

#define SCALE_ 0.08838834764831845f   // 1/sqrt(128)
#define MINV_  (-3.4028234663852886e38f)

typedef __bf16 bf16;
typedef bf16  bf16x4 __attribute__((ext_vector_type(4)));
typedef bf16  bf16x8 __attribute__((ext_vector_type(8)));
typedef float f32x4  __attribute__((ext_vector_type(4)));
typedef float f32x16 __attribute__((ext_vector_type(16)));
typedef float float4v __attribute__((ext_vector_type(4)));

#define LD8(p) (*(const bf16x8*)(p))

__device__ __forceinline__ f32x4 mfma16(bf16x8 a, bf16x8 b, f32x4 c) {
    return __builtin_amdgcn_mfma_f32_16x16x32_bf16(a, b, c, 0, 0, 0);
}
__device__ __forceinline__ f32x16 mfma32(bf16x8 a, bf16x8 b, f32x16 c) {
    return __builtin_amdgcn_mfma_f32_32x32x16_bf16(a, b, c, 0, 0, 0);
}

typedef const __attribute__((address_space(1))) void* gas_t;
typedef __attribute__((address_space(3))) void* sas_t;
__device__ __forceinline__ void gload_lds16(const void* g, void* l) {
    __builtin_amdgcn_global_load_lds((gas_t)g, (sas_t)l, 16, 0, 0);
}

// ---------------- prep kernels ----------------

__global__ __launch_bounds__(256) void cast_hidden_kernel(const float* __restrict__ X, bf16* __restrict__ Y)
{
    int i = (blockIdx.x * 256 + threadIdx.x) * 4;
    float4v v = *(const float4v*)(X + i);
    bf16x4 o; o.x = (bf16)v.x; o.y = (bf16)v.y; o.z = (bf16)v.z; o.w = (bf16)v.w;
    *(bf16x4*)(Y + i) = o;
}

// BT[n][k] = W[k][src(n)]; qmap: src = (n>>7)*384 + (n&127) (q columns of Wqkv), else src=n (Wo)
__global__ __launch_bounds__(256) void transpose_cast_kernel(const float* __restrict__ W, bf16* __restrict__ BT,
                                                             int srcStride, int qmap)
{
    __shared__ float tile[32][33];
    int k0 = blockIdx.x * 32, n0 = blockIdx.y * 32;
    int c = threadIdx.x & 31, r = threadIdx.x >> 5;   // r in 0..7
    int n = n0 + c;
    int src = qmap ? ((n >> 7) * 384 + (n & 127)) : n;
    #pragma unroll
    for (int rr = 0; rr < 32; rr += 8)
        tile[r + rr][c] = W[(size_t)(k0 + r + rr) * srcStride + src];
    __syncthreads();
    #pragma unroll
    for (int rr = 0; rr < 32; rr += 8)
        BT[(size_t)(n0 + r + rr) * 2048 + k0 + c] = (bf16)tile[c][r + rr];
}

// rows 2048..2303 of BT1: head-averaged k/v weight columns. Coalesced: thread=j, 1KB row segments.
__global__ __launch_bounds__(256) void bt1_kv_kernel(const float* __restrict__ Wqkv, bf16* __restrict__ BT1)
{
    int k0 = blockIdx.x * 16;
    int j = threadIdx.x;            // 0..255
    float acc[16];
    #pragma unroll
    for (int k = 0; k < 16; k++) acc[k] = 0.f;
    for (int h = 0; h < 16; h++) {
        #pragma unroll
        for (int k = 0; k < 16; k++)
            acc[k] += Wqkv[(size_t)(k0 + k) * 6144 + h * 384 + 128 + j];
    }
    #pragma unroll
    for (int k = 0; k < 16; k++)
        BT1[(size_t)(2048 + j) * 2048 + k0 + k] = (bf16)(acc[k] * 0.0625f);
}

__global__ void bias1_kernel(const float* __restrict__ bqkv, float* __restrict__ bias1)
{
    int c = blockIdx.x * 256 + threadIdx.x;
    if (c >= 2304) return;
    if (c < 2048) bias1[c] = bqkv[(c >> 7) * 384 + (c & 127)];
    else {
        int j = c - 2048; float s = 0.f;
        for (int h = 0; h < 16; h++) s += bqkv[h * 384 + 128 + j];
        bias1[c] = s * 0.0625f;
    }
}

// ---------------- GEMM (m97 structure, 32x32x16 MFMA): C = A . BT^T + bias ----------------
// 128x128 tile, BK=64, global_load_lds width-16 staging, XOR swizzle on gather side.
// Wave tile 64x64 = 2x2 of 32x32; C/D: col=lane&31, row=(reg&3)+8*(reg>>2)+4*(lane>>5).
template<int OUT_BF16>
__global__ __launch_bounds__(256) void gemm_kernel(const bf16* __restrict__ A, const bf16* __restrict__ BT,
                                                   const float* __restrict__ bias, void* __restrict__ Cout,
                                                   int M, int N, int K)
{
    __shared__ __align__(16) bf16 As[128 * 64];
    __shared__ __align__(16) bf16 Bs[128 * 64];
    const int tid  = threadIdx.x;
    const int wv   = tid >> 6, lane = tid & 63, l32 = lane & 31, half = lane >> 5;
    const int wrow = wv >> 1, wcol = wv & 1;
    const int m0 = blockIdx.y * 128, n0 = blockIdx.x * 128;

    // staging geometry: issue j of wave wv covers flat chunk ids (wv*4+j)*64 + lane
    int rowS[4], colS[4];
    #pragma unroll
    for (int j = 0; j < 4; j++) {
        int flat = (wv * 4 + j) * 64 + lane;
        int row = flat >> 3, cp = flat & 7;
        rowS[j] = row;
        colS[j] = (cp ^ (row & 7)) * 8;
    }

    f32x16 acc[2][2];
    #pragma unroll
    for (int i = 0; i < 2; i++)
        #pragma unroll
        for (int j = 0; j < 2; j++)
            #pragma unroll
            for (int r = 0; r < 16; r++) acc[i][j][r] = 0.f;

    for (int kk = 0; kk < K; kk += 64) {
        __syncthreads();   // previous iter's frag reads done
        #pragma unroll
        for (int j = 0; j < 4; j++) {
            gload_lds16(A  + (size_t)(m0 + rowS[j]) * K + kk + colS[j], &As[(wv * 4 + j) * 512]);
            gload_lds16(BT + (size_t)(n0 + rowS[j]) * K + kk + colS[j], &Bs[(wv * 4 + j) * 512]);
        }
        __syncthreads();   // staging complete

        bf16x8 af[2][4], bfr[2][4];
        #pragma unroll
        for (int mt = 0; mt < 2; mt++) {
            int row = wrow * 64 + mt * 32 + l32;
            #pragma unroll
            for (int k16 = 0; k16 < 4; k16++) {
                int lc = k16 * 2 + half;
                af[mt][k16] = LD8(&As[row * 64 + ((lc ^ (row & 7)) * 8)]);
            }
        }
        #pragma unroll
        for (int nt = 0; nt < 2; nt++) {
            int row = wcol * 64 + nt * 32 + l32;
            #pragma unroll
            for (int k16 = 0; k16 < 4; k16++) {
                int lc = k16 * 2 + half;
                bfr[nt][k16] = LD8(&Bs[row * 64 + ((lc ^ (row & 7)) * 8)]);
            }
        }
        #pragma unroll
        for (int k16 = 0; k16 < 4; k16++)
            #pragma unroll
            for (int mt = 0; mt < 2; mt++)
                #pragma unroll
                for (int nt = 0; nt < 2; nt++)
                    acc[mt][nt] = mfma32(af[mt][k16], bfr[nt][k16], acc[mt][nt]);
    }

    #pragma unroll
    for (int mt = 0; mt < 2; mt++) {
        #pragma unroll
        for (int nt = 0; nt < 2; nt++) {
            int n = n0 + wcol * 64 + nt * 32 + l32;
            float bn = bias[n];
            #pragma unroll
            for (int r = 0; r < 16; r++) {
                int m = m0 + wrow * 64 + mt * 32 + (r & 3) + 8 * (r >> 2) + 4 * half;
                float v = acc[mt][nt][r] + bn;
                if (OUT_BF16) ((bf16*)Cout)[(size_t)m * N + n] = (bf16)v;
                else          ((float*)Cout)[(size_t)m * N + n] = v;
            }
        }
    }
}

// ---------------- rotary (in-place on C1 bf16): q (16 heads) + k_mean, first 32 dims ----------------
__global__ __launch_bounds__(320) void rotary_kernel(bf16* __restrict__ C1)
{
    int row = blockIdx.x;          // b*2048 + s
    int s = row & 2047;
    int t = threadIdx.x;
    if (t >= 272) return;          // 17 groups (16 q heads + k_mean) x 16 dim-pairs
    int g = t >> 4, dd = t & 15;
    bf16* ptr = C1 + (size_t)row * 2304 + (g < 16 ? g * 128 : 2048);
    float x0 = (float)ptr[dd], x1 = (float)ptr[dd + 16];
    const float L = 0.575646273248511f;  // ln(10000)/16
    float inv = __expf(-L * (float)dd);
    float ang = (float)s * inv;
    float c, si;
    __sincosf(ang, &si, &c);
    ptr[dd]      = (bf16)(x0 * c - x1 * si);
    ptr[dd + 16] = (bf16)(x1 * c + x0 * si);
}

// ---------------- vmT[b][d][s] = v_mean transposed ----------------
__global__ __launch_bounds__(256) void build_vmT_kernel(const bf16* __restrict__ C1, bf16* __restrict__ vmT)
{
    __shared__ float tile[32][33];
    int b = blockIdx.z;
    int s0 = blockIdx.x * 32, d0 = blockIdx.y * 32;
    int c = threadIdx.x & 31, r = threadIdx.x >> 5;
    #pragma unroll
    for (int rr = 0; rr < 32; rr += 8)
        tile[r + rr][c] = (float)C1[(size_t)(b * 2048 + s0 + r + rr) * 2304 + 2176 + d0 + c];
    __syncthreads();
    #pragma unroll
    for (int rr = 0; rr < 32; rr += 8)
        vmT[(size_t)(b * 128 + d0 + r + rr) * 2048 + s0 + c] = (bf16)tile[c][r + rr];
}

// ---------------- pretile K/V into MFMA fragment order; blockIdx.x==32 -> gathered global chunk ----------------
__global__ __launch_bounds__(256) void pretile_kernel(const bf16* __restrict__ C1, const bf16* __restrict__ vmT,
                                                      const int* __restrict__ gidx,
                                                      bf16* __restrict__ KF, bf16* __restrict__ VF)
{
    int c = blockIdx.x, b = blockIdx.y;
    bool isGlob = (c == 32);
    for (int i = 0; i < 8; i++) {
        int sid = threadIdx.x + i * 256;     // 0..2047
        int lane = sid & 63, fi = (sid >> 6) & 15;
        int l16 = lane & 15, quad = lane >> 4;
        if (sid < 1024) {
            int t = fi >> 2, ks = fi & 3;
            int pos = isGlob ? gidx[b * 64 + t * 16 + l16] : (c * 64 + t * 16 + l16);
            const bf16* src = C1 + (size_t)(b * 2048 + pos) * 2304 + 2048 + ks * 32 + quad * 8;
            *(bf16x8*)&KF[((size_t)(b * 33 + c) * 16 + fi) * 512 + lane * 8] = LD8(src);
        } else {
            int dt = fi >> 1, ks2 = fi & 1;
            int d = dt * 16 + l16;
            if (isGlob) {
                bf16 tmp[8];
                #pragma unroll
                for (int j = 0; j < 8; j++) {
                    int pos = gidx[b * 64 + ks2 * 32 + quad * 8 + j];
                    tmp[j] = vmT[(size_t)(b * 128 + d) * 2048 + pos];
                }
                #pragma unroll
                for (int j = 0; j < 8; j++)
                    VF[((size_t)(b * 33 + 32) * 16 + fi) * 512 + lane * 8 + j] = tmp[j];
            } else {
                const bf16* src = vmT + (size_t)(b * 128 + d) * 2048 + c * 64 + ks2 * 32 + quad * 8;
                *(bf16x8*)&VF[((size_t)(b * 33 + c) * 16 + fi) * 512 + lane * 8] = LD8(src);
            }
        }
    }
}

#define PSTRIDE 88

// ---------------- attention, first WIN=256 queries (causal): wave-autonomous, pretiled frags ----------------
__global__ __launch_bounds__(256) void attn0_kernel(const bf16* __restrict__ C1, const bf16* __restrict__ KF,
                                                    const bf16* __restrict__ VF, const float* __restrict__ mask,
                                                    bf16* __restrict__ attn)
{
    const int bx = blockIdx.x, h = blockIdx.y, b = blockIdx.z;
    const int tid = threadIdx.x, wv = tid >> 6, lane = tid & 63, quad = lane >> 4, l16 = lane & 15;
    const int q0 = (bx * 4 + wv) * 16;

    __shared__ __align__(16) bf16 Ps[4 * 16 * PSTRIDE];
    bf16* Pw = &Ps[wv * (16 * PSTRIDE)];

    bf16x8 af[4];
    const bf16* qbase = C1 + (size_t)(b * 2048 + q0 + l16) * 2304 + h * 128;
    #pragma unroll
    for (int ks = 0; ks < 4; ks++) af[ks] = LD8(qbase + ks * 32 + quad * 8);

    f32x4 m_run = (f32x4){MINV_, MINV_, MINV_, MINV_};
    f32x4 l_run = (f32x4){0.f, 0.f, 0.f, 0.f};
    f32x4 O[8];
    #pragma unroll
    for (int dt = 0; dt < 8; dt++) O[dt] = (f32x4){0.f, 0.f, 0.f, 0.f};

    for (int c = 0; c <= bx; c++) {
        const bf16* KFc = KF + ((size_t)(b * 33 + c) * 16) * 512;
        const bf16* VFc = VF + ((size_t)(b * 33 + c) * 16) * 512;

        f32x4 acc[4];
        #pragma unroll
        for (int t = 0; t < 4; t++) acc[t] = (f32x4){0.f, 0.f, 0.f, 0.f};
        #pragma unroll
        for (int t = 0; t < 4; t++)
            #pragma unroll
            for (int ks = 0; ks < 4; ks++)
                acc[t] = mfma16(af[ks], LD8(KFc + (size_t)(t * 4 + ks) * 512 + lane * 8), acc[t]);

        float sv[4][4];
        #pragma unroll
        for (int t = 0; t < 4; t++) {
            int key = c * 64 + t * 16 + l16;
            float addv = mask[b * 2048 + key];
            #pragma unroll
            for (int r = 0; r < 4; r++) {
                int q = q0 + quad * 4 + r;
                sv[t][r] = (key <= q) ? (acc[t][r] * SCALE_ + addv) : MINV_;
            }
        }

        f32x4 cm;
        #pragma unroll
        for (int r = 0; r < 4; r++) cm[r] = fmaxf(fmaxf(sv[0][r], sv[1][r]), fmaxf(sv[2][r], sv[3][r]));
        #pragma unroll
        for (int ms = 1; ms < 16; ms <<= 1)
            #pragma unroll
            for (int r = 0; r < 4; r++) cm[r] = fmaxf(cm[r], __shfl_xor(cm[r], ms, 64));

        f32x4 nm, alpha;
        #pragma unroll
        for (int r = 0; r < 4; r++) { nm[r] = fmaxf(m_run[r], cm[r]); alpha[r] = __expf(m_run[r] - nm[r]); }

        float pv[4][4];
        f32x4 cs = (f32x4){0.f, 0.f, 0.f, 0.f};
        #pragma unroll
        for (int t = 0; t < 4; t++)
            #pragma unroll
            for (int r = 0; r < 4; r++) {
                pv[t][r] = __expf(sv[t][r] - nm[r]);   // MINV_ underflows to 0
                cs[r] += pv[t][r];
            }
        #pragma unroll
        for (int ms = 1; ms < 16; ms <<= 1)
            #pragma unroll
            for (int r = 0; r < 4; r++) cs[r] += __shfl_xor(cs[r], ms, 64);

        m_run = nm;
        #pragma unroll
        for (int r = 0; r < 4; r++) l_run[r] = l_run[r] * alpha[r] + cs[r];
        #pragma unroll
        for (int dt = 0; dt < 8; dt++)
            #pragma unroll
            for (int r = 0; r < 4; r++) O[dt][r] *= alpha[r];

        #pragma unroll
        for (int t = 0; t < 4; t++)
            #pragma unroll
            for (int r = 0; r < 4; r++)
                Pw[(quad * 4 + r) * PSTRIDE + t * 16 + l16] = (bf16)pv[t][r];
        bf16x8 pa0 = LD8(&Pw[l16 * PSTRIDE + quad * 8]);
        bf16x8 pa1 = LD8(&Pw[l16 * PSTRIDE + 32 + quad * 8]);

        #pragma unroll
        for (int dt = 0; dt < 8; dt++) {
            O[dt] = mfma16(pa0, LD8(VFc + (size_t)(dt * 2 + 0) * 512 + lane * 8), O[dt]);
            O[dt] = mfma16(pa1, LD8(VFc + (size_t)(dt * 2 + 1) * 512 + lane * 8), O[dt]);
        }
    }

    f32x4 invl;
    #pragma unroll
    for (int r = 0; r < 4; r++) invl[r] = 1.0f / l_run[r];
    #pragma unroll
    for (int dt = 0; dt < 8; dt++)
        #pragma unroll
        for (int r = 0; r < 4; r++) {
            int q = q0 + quad * 4 + r;
            attn[(size_t)(b * 2048 + q) * 2048 + h * 128 + dt * 16 + l16] = (bf16)(O[dt][r] * invl[r]);
        }
}

// ---------------- attention steps v3: barrier-free, wave-autonomous, pretiled frags ----------------
__global__ __launch_bounds__(256) void attn_steps3_kernel(const bf16* __restrict__ C1, const bf16* __restrict__ KF,
                                                          const bf16* __restrict__ VF, const float* __restrict__ mask,
                                                          const int* __restrict__ gidx, bf16* __restrict__ attn)
{
    const int sb = blockIdx.x, b = blockIdx.y;
    const int tid = threadIdx.x, wv = tid >> 6, lane = tid & 63, quad = lane >> 4, l16 = lane & 15;
    const int step = sb * 4 + wv, p = 256 + step;

    __shared__ __align__(16) bf16 Ps[4 * 16 * PSTRIDE];
    bf16* Pw = &Ps[wv * (16 * PSTRIDE)];

    bf16x8 af[4];
    const bf16* qrow = C1 + (size_t)(b * 2048 + p) * 2304;
    #pragma unroll
    for (int ks = 0; ks < 4; ks++) af[ks] = LD8(qrow + l16 * 128 + ks * 32 + quad * 8);

    int gix[4];
    #pragma unroll
    for (int t = 0; t < 4; t++) gix[t] = gidx[b * 64 + t * 16 + l16];

    f32x4 m_run = (f32x4){MINV_, MINV_, MINV_, MINV_};
    f32x4 l_run = (f32x4){0.f, 0.f, 0.f, 0.f};
    f32x4 O[8];
    #pragma unroll
    for (int dt = 0; dt < 8; dt++) O[dt] = (f32x4){0.f, 0.f, 0.f, 0.f};

    const int c0 = (step + 1) >> 6;

    for (int iter = 0; iter < 6; iter++) {
        int c;
        bool isGlob = (iter == 0);
        if (isGlob) c = 32;
        else { c = c0 + iter - 1; if (c > 31) break; }

        const bf16* KFc = KF + ((size_t)(b * 33 + c) * 16) * 512;
        const bf16* VFc = VF + ((size_t)(b * 33 + c) * 16) * 512;

        f32x4 acc[4];
        #pragma unroll
        for (int t = 0; t < 4; t++) acc[t] = (f32x4){0.f, 0.f, 0.f, 0.f};
        #pragma unroll
        for (int t = 0; t < 4; t++)
            #pragma unroll
            for (int ks = 0; ks < 4; ks++)
                acc[t] = mfma16(af[ks], LD8(KFc + (size_t)(t * 4 + ks) * 512 + lane * 8), acc[t]);

        float sv[4][4];
        bool vld[4];
        #pragma unroll
        for (int t = 0; t < 4; t++) {
            float addv = 0.f;
            if (isGlob) vld[t] = gix[t] < step;
            else {
                int pos = c * 64 + t * 16 + l16;
                vld[t] = (unsigned)(pos - step - 1) < 256u;
                addv = mask[b * 2048 + pos];
            }
            #pragma unroll
            for (int r = 0; r < 4; r++) sv[t][r] = vld[t] ? (acc[t][r] * SCALE_ + addv) : MINV_;
        }

        f32x4 cm;
        #pragma unroll
        for (int r = 0; r < 4; r++) cm[r] = fmaxf(fmaxf(sv[0][r], sv[1][r]), fmaxf(sv[2][r], sv[3][r]));
        #pragma unroll
        for (int ms = 1; ms < 16; ms <<= 1)
            #pragma unroll
            for (int r = 0; r < 4; r++) cm[r] = fmaxf(cm[r], __shfl_xor(cm[r], ms, 64));

        f32x4 nm, alpha;
        #pragma unroll
        for (int r = 0; r < 4; r++) { nm[r] = fmaxf(m_run[r], cm[r]); alpha[r] = __expf(m_run[r] - nm[r]); }

        float pv[4][4];
        f32x4 cs = (f32x4){0.f, 0.f, 0.f, 0.f};
        #pragma unroll
        for (int t = 0; t < 4; t++)
            #pragma unroll
            for (int r = 0; r < 4; r++) {
                pv[t][r] = vld[t] ? __expf(sv[t][r] - nm[r]) : 0.f;
                cs[r] += pv[t][r];
            }
        #pragma unroll
        for (int ms = 1; ms < 16; ms <<= 1)
            #pragma unroll
            for (int r = 0; r < 4; r++) cs[r] += __shfl_xor(cs[r], ms, 64);

        m_run = nm;
        #pragma unroll
        for (int r = 0; r < 4; r++) l_run[r] = l_run[r] * alpha[r] + cs[r];
        #pragma unroll
        for (int dt = 0; dt < 8; dt++)
            #pragma unroll
            for (int r = 0; r < 4; r++) O[dt][r] *= alpha[r];

        #pragma unroll
        for (int t = 0; t < 4; t++)
            #pragma unroll
            for (int r = 0; r < 4; r++)
                Pw[(quad * 4 + r) * PSTRIDE + t * 16 + l16] = (bf16)pv[t][r];
        bf16x8 pa0 = LD8(&Pw[l16 * PSTRIDE + quad * 8]);
        bf16x8 pa1 = LD8(&Pw[l16 * PSTRIDE + 32 + quad * 8]);

        #pragma unroll
        for (int dt = 0; dt < 8; dt++) {
            O[dt] = mfma16(pa0, LD8(VFc + (size_t)(dt * 2 + 0) * 512 + lane * 8), O[dt]);
            O[dt] = mfma16(pa1, LD8(VFc + (size_t)(dt * 2 + 1) * 512 + lane * 8), O[dt]);
        }
    }

    f32x4 invl;
    #pragma unroll
    for (int r = 0; r < 4; r++) invl[r] = 1.0f / l_run[r];
    #pragma unroll
    for (int dt = 0; dt < 8; dt++)
        #pragma unroll
        for (int r = 0; r < 4; r++) {
            int h = quad * 4 + r;
            attn[(size_t)(b * 2048 + p) * 2048 + h * 128 + dt * 16 + l16] = (bf16)(O[dt][r] * invl[r]);
        }
}

// ---------------- launch ----------------
extern "C" void kernel_launch(void* const* d_in, const int* in_sizes, int n_in,
                              void* d_out, int out_size, void* d_ws, size_t ws_size,
                              hipStream_t stream)
{
    const float* hidden = (const float*)d_in[0];
    const float* amask  = (const float*)d_in[1];
    const int*   gidx   = (const int*)d_in[2];
    const float* Wqkv   = (const float*)d_in[3];
    const float* bqkv   = (const float*)d_in[4];
    const float* Wo     = (const float*)d_in[5];
    const float* bo     = (const float*)d_in[6];

    char* ws = (char*)d_ws;
    size_t off = 0;
    auto take = [&](size_t bytes) -> char* {
        char* p = ws + off;
        off = (off + bytes + 255) & ~(size_t)255;
        return p;
    };
    bf16*  A16   = (bf16*)take(4096ull * 2048 * 2);   // hidden, bf16
    bf16*  BT1   = (bf16*)take(2304ull * 2048 * 2);   // [q cols | k-avg | v-avg]^T
    bf16*  BT2   = (bf16*)take(2048ull * 2048 * 2);   // Wo^T
    bf16*  C1    = (bf16*)take(4096ull * 2304 * 2);   // q(2048) | k_mean(128) | v_mean(128)
    bf16*  vmT   = (bf16*)take(2ull * 128 * 2048 * 2);
    bf16*  KF    = (bf16*)take(2ull * 33 * 16 * 512 * 2);
    bf16*  VF    = (bf16*)take(2ull * 33 * 16 * 512 * 2);
    bf16*  attnb = (bf16*)take(4096ull * 2048 * 2);
    float* bias1 = (float*)take(2304 * 4);

    cast_hidden_kernel<<<8192, 256, 0, stream>>>(hidden, A16);
    transpose_cast_kernel<<<dim3(64, 64), 256, 0, stream>>>(Wqkv, BT1, 6144, 1);
    bt1_kv_kernel<<<128, 256, 0, stream>>>(Wqkv, BT1);
    bias1_kernel<<<9, 256, 0, stream>>>(bqkv, bias1);
    transpose_cast_kernel<<<dim3(64, 64), 256, 0, stream>>>(Wo, BT2, 2048, 0);

    gemm_kernel<1><<<dim3(18, 32), 256, 0, stream>>>(A16, BT1, bias1, (void*)C1, 4096, 2304, 2048);

    rotary_kernel<<<4096, 320, 0, stream>>>(C1);
    build_vmT_kernel<<<dim3(64, 4, 2), 256, 0, stream>>>(C1, vmT);
    pretile_kernel<<<dim3(33, 2), 256, 0, stream>>>(C1, vmT, gidx, KF, VF);

    attn0_kernel<<<dim3(4, 16, 2), 256, 0, stream>>>(C1, KF, VF, amask, attnb);
    attn_steps3_kernel<<<dim3(448, 2), 256, 0, stream>>>(C1, KF, VF, amask, gidx, attnb);

    gemm_kernel<0><<<dim3(16, 32), 256, 0, stream>>>(attnb, BT2, bo, d_out, 4096, 2048, 2048);

    (void)in_sizes; (void)n_in; (void)out_size; (void)ws_size;
}